// Round 1
// baseline (2896.657 us; speedup 1.0000x reference)
//
#include <hip/hip_runtime.h>
#include <stdint.h>

// Mamba-1.4B-like dims (fixed)
#define LSEQ 2048
#define HID  2048
#define IDIM 4096
#define NSTATE 16
#define RRANK 128
#define GDIM 160   // RRANK + 2*NSTATE

typedef _Float16 f16x8 __attribute__((ext_vector_type(8)));
typedef float f32x4 __attribute__((ext_vector_type(4)));

// ---------------------------------------------------------------------------
// f32 -> f16 elementwise convert
__global__ void f32_to_f16_kernel(const float* __restrict__ in, _Float16* __restrict__ out, int n) {
    int i = blockIdx.x * 256 + threadIdx.x;
    if (i < n) out[i] = (_Float16)in[i];
}

// ---------------------------------------------------------------------------
// transpose f32 (R x C) -> f16 (C x R)
__global__ void transpose_f32_f16_kernel(const float* __restrict__ in, _Float16* __restrict__ out,
                                         int R, int C) {
    __shared__ float tile[32][33];
    int bx = blockIdx.x;            // tile along C
    int by = blockIdx.y;            // tile along R
    int tx = threadIdx.x & 31;
    int ty = threadIdx.x >> 5;      // 0..7
    int r0 = by * 32, c0 = bx * 32;
    #pragma unroll
    for (int j = 0; j < 32; j += 8)
        tile[ty + j][tx] = in[(long)(r0 + ty + j) * C + c0 + tx];
    __syncthreads();
    #pragma unroll
    for (int j = 0; j < 32; j += 8)
        out[(long)(c0 + ty + j) * R + r0 + tx] = (_Float16)tile[tx][ty + j];
}

// ---------------------------------------------------------------------------
// GEMM: C(M,N) = A(M,K) @ Bt(N,K)^T, fp16 in, fp32 acc, CT out.
// M % 128 == 0, K % 32 == 0. N arbitrary (Bt must be allocated with rows
// padded up to multiple of 128; junk rows are masked at the C store).
// 256 threads = 4 waves, 2x2 wave grid, each wave 64x64 via 4x4 16x16 tiles.
#define BM 128
#define BN 128
#define BK 32

template <typename CT>
__global__ __launch_bounds__(256)
void gemm_bt_kernel(const _Float16* __restrict__ A, const _Float16* __restrict__ Bt,
                    CT* __restrict__ C, int M, int N, int K) {
    __shared__ _Float16 As[BM * BK];
    __shared__ _Float16 Bs[BN * BK];
    const int m0 = blockIdx.y * BM;
    const int n0 = blockIdx.x * BN;
    const int t = threadIdx.x;
    const int wave = t >> 6;
    const int lane = t & 63;
    const int wm = wave >> 1, wn = wave & 1;
    const int lrow = lane & 15;
    const int quad = lane >> 4;

    f32x4 acc[4][4];
    #pragma unroll
    for (int mi = 0; mi < 4; ++mi)
        #pragma unroll
        for (int ni = 0; ni < 4; ++ni)
            #pragma unroll
            for (int r = 0; r < 4; ++r)
                acc[mi][ni][r] = 0.f;

    // staging: 16B chunk c covers (row = c>>2, col = (c&3)*8); thread does c = t and t+256
    const int c0 = t, c1 = t + 256;
    const int ar0 = c0 >> 2, ac0 = (c0 & 3) * 8;
    const int ar1 = c1 >> 2, ac1 = (c1 & 3) * 8;

    for (int k0 = 0; k0 < K; k0 += BK) {
        uint4 va0 = *(const uint4*)(A + (long)(m0 + ar0) * K + k0 + ac0);
        uint4 va1 = *(const uint4*)(A + (long)(m0 + ar1) * K + k0 + ac1);
        uint4 vb0 = *(const uint4*)(Bt + (long)(n0 + ar0) * K + k0 + ac0);
        uint4 vb1 = *(const uint4*)(Bt + (long)(n0 + ar1) * K + k0 + ac1);
        *(uint4*)(As + c0 * 8) = va0;
        *(uint4*)(As + c1 * 8) = va1;
        *(uint4*)(Bs + c0 * 8) = vb0;
        *(uint4*)(Bs + c1 * 8) = vb1;
        __syncthreads();

        f16x8 af[4], bf[4];
        #pragma unroll
        for (int mi = 0; mi < 4; ++mi)
            af[mi] = *(const f16x8*)(As + (wm * 64 + mi * 16 + lrow) * BK + quad * 8);
        #pragma unroll
        for (int ni = 0; ni < 4; ++ni)
            bf[ni] = *(const f16x8*)(Bs + (wn * 64 + ni * 16 + lrow) * BK + quad * 8);
        #pragma unroll
        for (int mi = 0; mi < 4; ++mi)
            #pragma unroll
            for (int ni = 0; ni < 4; ++ni)
                acc[mi][ni] = __builtin_amdgcn_mfma_f32_16x16x32_f16(af[mi], bf[ni], acc[mi][ni], 0, 0, 0);
        __syncthreads();
    }

    #pragma unroll
    for (int mi = 0; mi < 4; ++mi) {
        #pragma unroll
        for (int ni = 0; ni < 4; ++ni) {
            int col = n0 + wn * 64 + ni * 16 + lrow;
            if (col < N) {
                #pragma unroll
                for (int r = 0; r < 4; ++r) {
                    int row = m0 + wm * 64 + mi * 16 + quad * 4 + r;
                    C[(long)row * N + col] = (CT)acc[mi][ni][r];
                }
            }
        }
    }
}

// ---------------------------------------------------------------------------
// depthwise causal conv (K=4) + bias + SiLU.  proj16 = (L, 2I) f16, hidden = cols [0,I)
__global__ void conv_silu_kernel(const _Float16* __restrict__ proj, const float* __restrict__ w,
                                 const float* __restrict__ b, _Float16* __restrict__ u16) {
    int idx = blockIdx.x * 256 + threadIdx.x;   // L*I
    int i = idx & (IDIM - 1);
    int t = idx >> 12;
    float4 wv = ((const float4*)w)[i];
    float acc = b[i];
    int base = t * (2 * IDIM) + i;
    if (t >= 3) {
        acc += (float)proj[base - 3 * 2 * IDIM] * wv.x;
        acc += (float)proj[base - 2 * 2 * IDIM] * wv.y;
        acc += (float)proj[base - 1 * 2 * IDIM] * wv.z;
        acc += (float)proj[base] * wv.w;
    } else {
        if (t >= 3) acc += (float)proj[base - 3 * 2 * IDIM] * wv.x;
        if (t >= 2) acc += (float)proj[base - 2 * 2 * IDIM] * wv.y;
        if (t >= 1) acc += (float)proj[base - 1 * 2 * IDIM] * wv.z;
        acc += (float)proj[base] * wv.w;
    }
    float s = acc / (1.f + __expf(-acc));
    u16[idx] = (_Float16)s;
}

// ---------------------------------------------------------------------------
// extract dt_in (first RRANK cols of ssm_in) as f16
__global__ void extract_dtin_kernel(const float* __restrict__ ssm, _Float16* __restrict__ dtin) {
    int idx = blockIdx.x * 256 + threadIdx.x;   // L*RRANK
    int t = idx >> 7;
    int r = idx & (RRANK - 1);
    dtin[idx] = (_Float16)ssm[t * GDIM + r];
}

// ---------------------------------------------------------------------------
__device__ __forceinline__ float softplus_f(float x) {
    if (x > 20.f) return x;
    return log1pf(__expf(x));
}

// selective scan: one thread per (channel i, state n). 16-lane shuffle reduce.
// Writes yfull = (y_ssm + u*D) * silu(gate) as f16 (L, I).
__global__ void scan_kernel(const float* __restrict__ dtlin, const float* __restrict__ dtb,
                            const float* __restrict__ ssm, const _Float16* __restrict__ u16,
                            const _Float16* __restrict__ proj, const float* __restrict__ A_log,
                            const float* __restrict__ Dp, _Float16* __restrict__ y16) {
    int tid = blockIdx.x * 256 + threadIdx.x;   // I*NSTATE = 65536
    int i = tid >> 4;
    int n = tid & 15;
    float A = -__expf(A_log[i * NSTATE + n]);
    float dtbi = dtb[i];
    float Dv = Dp[i];
    float s = 0.f;
    for (int t = 0; t < LSEQ; ++t) {
        float x = dtlin[t * IDIM + i] + dtbi;
        float dt = softplus_f(x);
        float uv = (float)u16[t * IDIM + i];
        float Bv = ssm[t * GDIM + RRANK + n];
        float Cv = ssm[t * GDIM + RRANK + NSTATE + n];
        float dA = __expf(dt * A);
        s = s * dA + dt * uv * Bv;
        float y = s * Cv;
        y += __shfl_xor(y, 1);
        y += __shfl_xor(y, 2);
        y += __shfl_xor(y, 4);
        y += __shfl_xor(y, 8);
        if (n == 0) {
            float g = (float)proj[t * (2 * IDIM) + IDIM + i];
            float out = (y + uv * Dv) * (g / (1.f + __expf(-g)));
            y16[t * IDIM + i] = (_Float16)out;
        }
    }
}

// ---------------------------------------------------------------------------
extern "C" void kernel_launch(void* const* d_in, const int* in_sizes, int n_in,
                              void* d_out, int out_size, void* d_ws, size_t ws_size,
                              hipStream_t stream) {
    const float* x_in  = (const float*)d_in[0];   // (L, H)
    const float* w_in  = (const float*)d_in[1];   // (H, 2I)
    const float* cw    = (const float*)d_in[2];   // (I, 1, 4)
    const float* cb    = (const float*)d_in[3];   // (I)
    const float* xw    = (const float*)d_in[4];   // (I, GDIM)
    const float* dtw   = (const float*)d_in[5];   // (R, I)
    const float* dtb   = (const float*)d_in[6];   // (I)
    const float* alog  = (const float*)d_in[7];   // (I, N)
    const float* Dp    = (const float*)d_in[8];   // (I)
    const float* ow    = (const float*)d_in[9];   // (I, H)
    float* out = (float*)d_out;

    char* p = (char*)d_ws;
    auto alloc = [&](size_t bytes) { char* r = p; p += (bytes + 255) & ~255ull; return r; };
    _Float16* Xf    = (_Float16*)alloc((size_t)LSEQ * HID * 2);          // 8 MB
    _Float16* Wt1   = (_Float16*)alloc((size_t)2 * IDIM * HID * 2);      // 32 MB  (2I, H)
    _Float16* proj  = (_Float16*)alloc((size_t)LSEQ * 2 * IDIM * 2);     // 32 MB  (L, 2I)
    _Float16* u16   = (_Float16*)alloc((size_t)LSEQ * IDIM * 2);         // 16 MB
    _Float16* Wt2   = (_Float16*)alloc((size_t)256 * IDIM * 2);          // 2 MB (GDIM padded to 256, I)
    float*    ssm   = (float*)alloc((size_t)LSEQ * GDIM * 4);            // 1.25 MB
    _Float16* dtin  = (_Float16*)alloc((size_t)LSEQ * RRANK * 2);        // 0.5 MB
    _Float16* Wt3   = (_Float16*)alloc((size_t)IDIM * RRANK * 2);        // 1 MB (I, R)
    float*    dtlin = (float*)alloc((size_t)LSEQ * IDIM * 4);            // 32 MB
    _Float16* Wt4   = (_Float16*)alloc((size_t)HID * IDIM * 2);          // 16 MB (H, I)
    _Float16* y16   = (_Float16*)alloc((size_t)LSEQ * IDIM * 2);         // 16 MB

    // 1. convert input
    f32_to_f16_kernel<<<(LSEQ * HID) / 256, 256, 0, stream>>>(x_in, Xf, LSEQ * HID);
    // 2. transpose weights (f32 -> f16)
    transpose_f32_f16_kernel<<<dim3(2 * IDIM / 32, HID / 32), 256, 0, stream>>>(w_in, Wt1, HID, 2 * IDIM);
    transpose_f32_f16_kernel<<<dim3(GDIM / 32, IDIM / 32), 256, 0, stream>>>(xw, Wt2, IDIM, GDIM);
    transpose_f32_f16_kernel<<<dim3(IDIM / 32, RRANK / 32), 256, 0, stream>>>(dtw, Wt3, RRANK, IDIM);
    transpose_f32_f16_kernel<<<dim3(HID / 32, IDIM / 32), 256, 0, stream>>>(ow, Wt4, IDIM, HID);
    // 3. in_proj GEMM: (L,H) @ (H,2I) -> proj (L,2I) f16
    gemm_bt_kernel<_Float16><<<dim3(2 * IDIM / BN, LSEQ / BM), 256, 0, stream>>>(
        Xf, Wt1, proj, LSEQ, 2 * IDIM, HID);
    // 4. causal depthwise conv + SiLU -> u16
    conv_silu_kernel<<<(LSEQ * IDIM) / 256, 256, 0, stream>>>(proj, cw, cb, u16);
    // 5. x_proj GEMM: (L,I) @ (I,GDIM) -> ssm (L,160) f32
    gemm_bt_kernel<float><<<dim3((GDIM + BN - 1) / BN, LSEQ / BM), 256, 0, stream>>>(
        u16, Wt2, ssm, LSEQ, GDIM, IDIM);
    // 6. dt_in extract
    extract_dtin_kernel<<<(LSEQ * RRANK) / 256, 256, 0, stream>>>(ssm, dtin);
    // 7. dt_proj GEMM: (L,R) @ (R,I) -> dtlin (L,I) f32
    gemm_bt_kernel<float><<<dim3(IDIM / BN, LSEQ / BM), 256, 0, stream>>>(
        dtin, Wt3, dtlin, LSEQ, IDIM, RRANK);
    // 8. selective scan + gating -> y16
    scan_kernel<<<(IDIM * NSTATE) / 256, 256, 0, stream>>>(
        dtlin, dtb, ssm, u16, proj, alog, Dp, y16);
    // 9. out_proj GEMM: (L,I) @ (I,H) -> out f32
    gemm_bt_kernel<float><<<dim3(HID / BN, LSEQ / BM), 256, 0, stream>>>(
        y16, Wt4, out, LSEQ, HID, IDIM);
}

// Round 2
// 657.639 us; speedup vs baseline: 4.4046x; 4.4046x over previous
//
#include <hip/hip_runtime.h>
#include <stdint.h>

// Mamba-1.4B-like dims (fixed)
#define LSEQ 2048
#define HID  2048
#define IDIM 4096
#define NSTATE 16
#define RRANK 128
#define GDIM 160   // RRANK + 2*NSTATE

// chunked scan
#define GCHUNK 64
#define TCHUNK (LSEQ / GCHUNK)   // 32

typedef _Float16 f16x8 __attribute__((ext_vector_type(8)));
typedef float f32x4 __attribute__((ext_vector_type(4)));

// ---------------------------------------------------------------------------
// f32 -> f16 elementwise convert
__global__ void f32_to_f16_kernel(const float* __restrict__ in, _Float16* __restrict__ out, int n) {
    int i = blockIdx.x * 256 + threadIdx.x;
    if (i < n) out[i] = (_Float16)in[i];
}

// ---------------------------------------------------------------------------
// transpose f32 (R x C) -> f16 (C x R)
__global__ void transpose_f32_f16_kernel(const float* __restrict__ in, _Float16* __restrict__ out,
                                         int R, int C) {
    __shared__ float tile[32][33];
    int bx = blockIdx.x;            // tile along C
    int by = blockIdx.y;            // tile along R
    int tx = threadIdx.x & 31;
    int ty = threadIdx.x >> 5;      // 0..7
    int r0 = by * 32, c0 = bx * 32;
    #pragma unroll
    for (int j = 0; j < 32; j += 8)
        tile[ty + j][tx] = in[(long)(r0 + ty + j) * C + c0 + tx];
    __syncthreads();
    #pragma unroll
    for (int j = 0; j < 32; j += 8)
        out[(long)(c0 + ty + j) * R + r0 + tx] = (_Float16)tile[tx][ty + j];
}

// ---------------------------------------------------------------------------
// GEMM: C(M,N) = A(M,K) @ Bt(N,K)^T, fp16 in, fp32 acc, CT out.
#define BM 128
#define BN 128
#define BK 32

template <typename CT>
__global__ __launch_bounds__(256)
void gemm_bt_kernel(const _Float16* __restrict__ A, const _Float16* __restrict__ Bt,
                    CT* __restrict__ C, int M, int N, int K) {
    __shared__ _Float16 As[BM * BK];
    __shared__ _Float16 Bs[BN * BK];
    const int m0 = blockIdx.y * BM;
    const int n0 = blockIdx.x * BN;
    const int t = threadIdx.x;
    const int wave = t >> 6;
    const int lane = t & 63;
    const int wm = wave >> 1, wn = wave & 1;
    const int lrow = lane & 15;
    const int quad = lane >> 4;

    f32x4 acc[4][4];
    #pragma unroll
    for (int mi = 0; mi < 4; ++mi)
        #pragma unroll
        for (int ni = 0; ni < 4; ++ni)
            #pragma unroll
            for (int r = 0; r < 4; ++r)
                acc[mi][ni][r] = 0.f;

    const int c0 = t, c1 = t + 256;
    const int ar0 = c0 >> 2, ac0 = (c0 & 3) * 8;
    const int ar1 = c1 >> 2, ac1 = (c1 & 3) * 8;

    for (int k0 = 0; k0 < K; k0 += BK) {
        uint4 va0 = *(const uint4*)(A + (long)(m0 + ar0) * K + k0 + ac0);
        uint4 va1 = *(const uint4*)(A + (long)(m0 + ar1) * K + k0 + ac1);
        uint4 vb0 = *(const uint4*)(Bt + (long)(n0 + ar0) * K + k0 + ac0);
        uint4 vb1 = *(const uint4*)(Bt + (long)(n0 + ar1) * K + k0 + ac1);
        *(uint4*)(As + c0 * 8) = va0;
        *(uint4*)(As + c1 * 8) = va1;
        *(uint4*)(Bs + c0 * 8) = vb0;
        *(uint4*)(Bs + c1 * 8) = vb1;
        __syncthreads();

        f16x8 af[4], bf[4];
        #pragma unroll
        for (int mi = 0; mi < 4; ++mi)
            af[mi] = *(const f16x8*)(As + (wm * 64 + mi * 16 + lrow) * BK + quad * 8);
        #pragma unroll
        for (int ni = 0; ni < 4; ++ni)
            bf[ni] = *(const f16x8*)(Bs + (wn * 64 + ni * 16 + lrow) * BK + quad * 8);
        #pragma unroll
        for (int mi = 0; mi < 4; ++mi)
            #pragma unroll
            for (int ni = 0; ni < 4; ++ni)
                acc[mi][ni] = __builtin_amdgcn_mfma_f32_16x16x32_f16(af[mi], bf[ni], acc[mi][ni], 0, 0, 0);
        __syncthreads();
    }

    #pragma unroll
    for (int mi = 0; mi < 4; ++mi) {
        #pragma unroll
        for (int ni = 0; ni < 4; ++ni) {
            int col = n0 + wn * 64 + ni * 16 + lrow;
            if (col < N) {
                #pragma unroll
                for (int r = 0; r < 4; ++r) {
                    int row = m0 + wm * 64 + mi * 16 + quad * 4 + r;
                    C[(long)row * N + col] = (CT)acc[mi][ni][r];
                }
            }
        }
    }
}

// ---------------------------------------------------------------------------
// depthwise causal conv (K=4) + bias + SiLU.  proj = (L, 2I) f16, hidden = cols [0,I)
__global__ void conv_silu_kernel(const _Float16* __restrict__ proj, const float* __restrict__ w,
                                 const float* __restrict__ b, _Float16* __restrict__ u16) {
    int idx = blockIdx.x * 256 + threadIdx.x;   // L*I
    int i = idx & (IDIM - 1);
    int t = idx >> 12;
    float4 wv = ((const float4*)w)[i];
    float acc = b[i];
    int base = t * (2 * IDIM) + i;
    if (t >= 3) acc += (float)proj[base - 3 * 2 * IDIM] * wv.x;
    if (t >= 2) acc += (float)proj[base - 2 * 2 * IDIM] * wv.y;
    if (t >= 1) acc += (float)proj[base - 1 * 2 * IDIM] * wv.z;
    acc += (float)proj[base] * wv.w;
    float s = acc / (1.f + __expf(-acc));
    u16[idx] = (_Float16)s;
}

// ---------------------------------------------------------------------------
// extract dt_in (first RRANK cols of ssm_in) as f16
__global__ void extract_dtin_kernel(const float* __restrict__ ssm, _Float16* __restrict__ dtin) {
    int idx = blockIdx.x * 256 + threadIdx.x;   // L*RRANK
    int t = idx >> 7;
    int r = idx & (RRANK - 1);
    dtin[idx] = (_Float16)ssm[t * GDIM + r];
}

// ---------------------------------------------------------------------------
__device__ __forceinline__ float softplus_f(float x) {
    if (x > 20.f) return x;
    return log1pf(__expf(x));
}
__device__ __forceinline__ float silu_f(float x) {
    return x / (1.f + __expf(-x));
}

// ---------------------------------------------------------------------------
// Chunked selective scan. One thread per channel i, 16 states in registers.
// Pass 1: per chunk c, compute P[n] = prod(dA) and local end-state S[n] (zero init).
__global__ __launch_bounds__(256)
void scan_pass1_kernel(const float* __restrict__ dtlin, const float* __restrict__ dtb,
                       const float* __restrict__ ssm, const _Float16* __restrict__ u16,
                       const float* __restrict__ A_log,
                       float* __restrict__ Pc, float* __restrict__ Sc) {
    const int c = blockIdx.y;
    const int i = blockIdx.x * 256 + threadIdx.x;

    __shared__ float Bs[TCHUNK * 16];
    for (int idx = threadIdx.x; idx < TCHUNK * 16; idx += 256) {
        int t = idx >> 4, n = idx & 15;
        Bs[idx] = ssm[(c * TCHUNK + t) * GDIM + RRANK + n];
    }
    __syncthreads();

    float A[16];
    {
        const float4* Ap = (const float4*)(A_log + i * 16);
        #pragma unroll
        for (int q = 0; q < 4; ++q) {
            float4 v = Ap[q];
            A[q * 4 + 0] = -__expf(v.x);
            A[q * 4 + 1] = -__expf(v.y);
            A[q * 4 + 2] = -__expf(v.z);
            A[q * 4 + 3] = -__expf(v.w);
        }
    }
    const float dtbi = dtb[i];

    float s[16], p[16];
    #pragma unroll
    for (int n = 0; n < 16; ++n) { s[n] = 0.f; p[n] = 1.f; }

    long base = (long)c * TCHUNK * IDIM + i;
    for (int t = 0; t < TCHUNK; ++t) {
        float dt = softplus_f(dtlin[base + (long)t * IDIM] + dtbi);
        float dtu = dt * (float)u16[base + (long)t * IDIM];
        #pragma unroll
        for (int n = 0; n < 16; ++n) {
            float dA = __expf(dt * A[n]);
            s[n] = s[n] * dA + dtu * Bs[t * 16 + n];
            p[n] *= dA;
        }
    }

    long o = ((long)c * IDIM + i) * 16;
    #pragma unroll
    for (int q = 0; q < 4; ++q) {
        *(float4*)(Pc + o + q * 4) = make_float4(p[q*4+0], p[q*4+1], p[q*4+2], p[q*4+3]);
        *(float4*)(Sc + o + q * 4) = make_float4(s[q*4+0], s[q*4+1], s[q*4+2], s[q*4+3]);
    }
}

// Combine: sequential over G chunks per (i,n); Init overwrites Sc in place.
__global__ void scan_combine_kernel(const float* __restrict__ Pc, float* __restrict__ ScInit) {
    int tid = blockIdx.x * 256 + threadIdx.x;   // I*16
    float carry = 0.f;
    for (int c = 0; c < GCHUNK; ++c) {
        long o = (long)c * (IDIM * 16) + tid;
        float pv = Pc[o];
        float sv = ScInit[o];
        ScInit[o] = carry;          // becomes Init[c]
        carry = carry * pv + sv;
    }
}

// Pass 3: re-run each chunk from its true initial state, emit gated output.
__global__ __launch_bounds__(256)
void scan_pass3_kernel(const float* __restrict__ dtlin, const float* __restrict__ dtb,
                       const float* __restrict__ ssm, const _Float16* __restrict__ u16,
                       const _Float16* __restrict__ proj, const float* __restrict__ A_log,
                       const float* __restrict__ Dp, const float* __restrict__ Init,
                       _Float16* __restrict__ y16) {
    const int c = blockIdx.y;
    const int i = blockIdx.x * 256 + threadIdx.x;

    __shared__ float Bs[TCHUNK * 16];
    __shared__ float Cs[TCHUNK * 16];
    for (int idx = threadIdx.x; idx < TCHUNK * 16; idx += 256) {
        int t = idx >> 4, n = idx & 15;
        Bs[idx] = ssm[(c * TCHUNK + t) * GDIM + RRANK + n];
        Cs[idx] = ssm[(c * TCHUNK + t) * GDIM + RRANK + NSTATE + n];
    }
    __syncthreads();

    float A[16];
    {
        const float4* Ap = (const float4*)(A_log + i * 16);
        #pragma unroll
        for (int q = 0; q < 4; ++q) {
            float4 v = Ap[q];
            A[q * 4 + 0] = -__expf(v.x);
            A[q * 4 + 1] = -__expf(v.y);
            A[q * 4 + 2] = -__expf(v.z);
            A[q * 4 + 3] = -__expf(v.w);
        }
    }
    const float dtbi = dtb[i];
    const float Dv = Dp[i];

    float s[16];
    {
        long o = ((long)c * IDIM + i) * 16;
        #pragma unroll
        for (int q = 0; q < 4; ++q) {
            float4 v = *(const float4*)(Init + o + q * 4);
            s[q*4+0] = v.x; s[q*4+1] = v.y; s[q*4+2] = v.z; s[q*4+3] = v.w;
        }
    }

    long base = (long)c * TCHUNK * IDIM + i;
    for (int t = 0; t < TCHUNK; ++t) {
        float dt = softplus_f(dtlin[base + (long)t * IDIM] + dtbi);
        float uv = (float)u16[base + (long)t * IDIM];
        float dtu = dt * uv;
        float y = 0.f;
        #pragma unroll
        for (int n = 0; n < 16; ++n) {
            float dA = __expf(dt * A[n]);
            s[n] = s[n] * dA + dtu * Bs[t * 16 + n];
            y += s[n] * Cs[t * 16 + n];
        }
        int tg = c * TCHUNK + t;
        float g = (float)proj[(long)tg * (2 * IDIM) + IDIM + i];
        float out = (y + uv * Dv) * silu_f(g);
        y16[base + (long)t * IDIM] = (_Float16)out;
    }
}

// ---------------------------------------------------------------------------
extern "C" void kernel_launch(void* const* d_in, const int* in_sizes, int n_in,
                              void* d_out, int out_size, void* d_ws, size_t ws_size,
                              hipStream_t stream) {
    const float* x_in  = (const float*)d_in[0];   // (L, H)
    const float* w_in  = (const float*)d_in[1];   // (H, 2I)
    const float* cw    = (const float*)d_in[2];   // (I, 1, 4)
    const float* cb    = (const float*)d_in[3];   // (I)
    const float* xw    = (const float*)d_in[4];   // (I, GDIM)
    const float* dtw   = (const float*)d_in[5];   // (R, I)
    const float* dtb   = (const float*)d_in[6];   // (I)
    const float* alog  = (const float*)d_in[7];   // (I, N)
    const float* Dp    = (const float*)d_in[8];   // (I)
    const float* ow    = (const float*)d_in[9];   // (I, H)
    float* out = (float*)d_out;

    char* p = (char*)d_ws;
    auto alloc = [&](size_t bytes) { char* r = p; p += (bytes + 255) & ~255ull; return r; };
    _Float16* Xf    = (_Float16*)alloc((size_t)LSEQ * HID * 2);          // 8 MB
    _Float16* Wt1   = (_Float16*)alloc((size_t)2 * IDIM * HID * 2);      // 33.5 MB  (2I, H)
    _Float16* proj  = (_Float16*)alloc((size_t)LSEQ * 2 * IDIM * 2);     // 33.5 MB  (L, 2I)
    _Float16* u16   = (_Float16*)alloc((size_t)LSEQ * IDIM * 2);         // 16.8 MB
    _Float16* Wt2   = (_Float16*)alloc((size_t)256 * IDIM * 2);          // 2 MB (GDIM->256 pad, I)
    float*    ssm   = (float*)alloc((size_t)LSEQ * GDIM * 4);            // 1.25 MB
    _Float16* dtin  = (_Float16*)alloc((size_t)LSEQ * RRANK * 2);        // 0.5 MB
    _Float16* Wt3   = (_Float16*)alloc((size_t)IDIM * RRANK * 2);        // 1 MB (I, R)
    float*    dtlin = (float*)alloc((size_t)LSEQ * IDIM * 4);            // 33.5 MB
    _Float16* Wt4   = (_Float16*)alloc((size_t)HID * IDIM * 2);          // 16.8 MB (H, I)
    _Float16* y16   = (_Float16*)alloc((size_t)LSEQ * IDIM * 2);         // 16.8 MB

    // chunk-state buffers alias Wt1 (dead after in_proj GEMM):
    // Pc + Sc = 2 * G*I*16*4 = 33554432 B == sizeof(Wt1) exactly.
    float* Pc = (float*)Wt1;
    float* Sc = Pc + (size_t)GCHUNK * IDIM * 16;

    // 1. convert input
    f32_to_f16_kernel<<<(LSEQ * HID) / 256, 256, 0, stream>>>(x_in, Xf, LSEQ * HID);
    // 2. transpose weights (f32 -> f16)
    transpose_f32_f16_kernel<<<dim3(2 * IDIM / 32, HID / 32), 256, 0, stream>>>(w_in, Wt1, HID, 2 * IDIM);
    transpose_f32_f16_kernel<<<dim3(GDIM / 32, IDIM / 32), 256, 0, stream>>>(xw, Wt2, IDIM, GDIM);
    transpose_f32_f16_kernel<<<dim3(IDIM / 32, RRANK / 32), 256, 0, stream>>>(dtw, Wt3, RRANK, IDIM);
    transpose_f32_f16_kernel<<<dim3(HID / 32, IDIM / 32), 256, 0, stream>>>(ow, Wt4, IDIM, HID);
    // 3. in_proj GEMM: (L,H) @ (H,2I) -> proj (L,2I) f16
    gemm_bt_kernel<_Float16><<<dim3(2 * IDIM / BN, LSEQ / BM), 256, 0, stream>>>(
        Xf, Wt1, proj, LSEQ, 2 * IDIM, HID);
    // 4. causal depthwise conv + SiLU -> u16
    conv_silu_kernel<<<(LSEQ * IDIM) / 256, 256, 0, stream>>>(proj, cw, cb, u16);
    // 5. x_proj GEMM: (L,I) @ (I,GDIM) -> ssm (L,160) f32
    gemm_bt_kernel<float><<<dim3((GDIM + BN - 1) / BN, LSEQ / BM), 256, 0, stream>>>(
        u16, Wt2, ssm, LSEQ, GDIM, IDIM);
    // 6. dt_in extract
    extract_dtin_kernel<<<(LSEQ * RRANK) / 256, 256, 0, stream>>>(ssm, dtin);
    // 7. dt_proj GEMM: (L,R) @ (R,I) -> dtlin (L,I) f32
    gemm_bt_kernel<float><<<dim3(IDIM / BN, LSEQ / BM), 256, 0, stream>>>(
        dtin, Wt3, dtlin, LSEQ, IDIM, RRANK);
    // 8. chunked selective scan
    scan_pass1_kernel<<<dim3(IDIM / 256, GCHUNK), 256, 0, stream>>>(
        dtlin, dtb, ssm, u16, alog, Pc, Sc);
    scan_combine_kernel<<<(IDIM * NSTATE) / 256, 256, 0, stream>>>(Pc, Sc);
    scan_pass3_kernel<<<dim3(IDIM / 256, GCHUNK), 256, 0, stream>>>(
        dtlin, dtb, ssm, u16, proj, alog, Dp, Sc, y16);
    // 9. out_proj GEMM: (L,I) @ (I,H) -> out f32
    gemm_bt_kernel<float><<<dim3(HID / BN, LSEQ / BM), 256, 0, stream>>>(
        y16, Wt4, out, LSEQ, HID, IDIM);
}

// Round 3
// 552.594 us; speedup vs baseline: 5.2419x; 1.1901x over previous
//
#include <hip/hip_runtime.h>
#include <stdint.h>

// Mamba-1.4B-like dims (fixed)
#define LSEQ 2048
#define HID  2048
#define IDIM 4096
#define NSTATE 16
#define RRANK 128
#define GDIM 160   // RRANK + 2*NSTATE

// chunked scan
#define GCHUNK 64
#define TCHUNK (LSEQ / GCHUNK)   // 32

typedef _Float16 f16x8 __attribute__((ext_vector_type(8)));
typedef float f32x4 __attribute__((ext_vector_type(4)));

#define GLOAD_LDS16(g, l) __builtin_amdgcn_global_load_lds( \
    (const __attribute__((address_space(1))) void*)(g),     \
    (__attribute__((address_space(3))) void*)(l), 16, 0, 0)

// ---------------------------------------------------------------------------
__global__ void f32_to_f16_kernel(const float* __restrict__ in, _Float16* __restrict__ out, int n) {
    int i = blockIdx.x * 256 + threadIdx.x;
    if (i < n) out[i] = (_Float16)in[i];
}

// ---------------------------------------------------------------------------
// transpose f32 (R x C) -> f16 (C x R)
__global__ void transpose_f32_f16_kernel(const float* __restrict__ in, _Float16* __restrict__ out,
                                         int R, int C) {
    __shared__ float tile[32][33];
    int bx = blockIdx.x;
    int by = blockIdx.y;
    int tx = threadIdx.x & 31;
    int ty = threadIdx.x >> 5;
    int r0 = by * 32, c0 = bx * 32;
    #pragma unroll
    for (int j = 0; j < 32; j += 8)
        tile[ty + j][tx] = in[(long)(r0 + ty + j) * C + c0 + tx];
    __syncthreads();
    #pragma unroll
    for (int j = 0; j < 32; j += 8)
        out[(long)(c0 + ty + j) * R + r0 + tx] = (_Float16)tile[tx][ty + j];
}

// ---------------------------------------------------------------------------
// GEMM: C = A(M,K) @ Bt(N,K)^T, fp16 in, fp32 acc. BM=128 fixed, BN_ templated.
// global_load_lds (16B DMA) staging + XOR chunk swizzle (chunk c of row r
// stored at position c ^ ((r>>1)&3)) -> conflict-free ds_read_b128.
// Optional K-split: blockIdx.z selects k-range [z*kc, z*kc+kc), output slab z.
#define BM 128
#define BK 32

template <typename CT, int BN_>
__global__ __launch_bounds__(256)
void gemm_bt_kernel(const _Float16* __restrict__ A, const _Float16* __restrict__ Bt,
                    CT* __restrict__ C, int M, int N, int K, int kc) {
    constexpr int NI = BN_ / 32;          // 16-col tiles per wave
    __shared__ _Float16 As[BM * BK];
    __shared__ _Float16 Bs[BN_ * BK];
    const int m0 = blockIdx.y * BM;
    const int n0 = blockIdx.x * BN_;
    const int t = threadIdx.x;
    const int wave = t >> 6;
    const int lane = t & 63;
    const int wm = wave >> 1, wn = wave & 1;
    const int lrow = lane & 15;
    const int quad = lane >> 4;
    // loop-invariant swizzled chunk offset for fragment reads
    const int qoff = (quad * 8) ^ (((lrow >> 1) & 3) * 8);

    f32x4 acc[4][NI];
    #pragma unroll
    for (int mi = 0; mi < 4; ++mi)
        #pragma unroll
        for (int ni = 0; ni < NI; ++ni)
            #pragma unroll
            for (int r = 0; r < 4; ++r)
                acc[mi][ni][r] = 0.f;

    // A staging: 512 chunks of 16B; wave covers [wave*128, wave*128+128), 2 issues
    int ra[2], ca[2];
    #pragma unroll
    for (int j = 0; j < 2; ++j) {
        int p = wave * 128 + j * 64 + lane;
        ra[j] = p >> 2;
        ca[j] = ((p & 3) ^ ((ra[j] >> 1) & 3)) * 8;
    }
    // B staging: BN_*4 chunks; wave covers BN_ chunks, BN_/64 issues
    int rb[BN_ / 64], cb_[BN_ / 64];
    #pragma unroll
    for (int j = 0; j < BN_ / 64; ++j) {
        int p = wave * BN_ + j * 64 + lane;
        rb[j] = p >> 2;
        cb_[j] = ((p & 3) ^ ((rb[j] >> 1) & 3)) * 8;
    }

    const int k_begin = blockIdx.z * kc;
    const int k_end = k_begin + kc;

    for (int kk = k_begin; kk < k_end; kk += BK) {
        #pragma unroll
        for (int j = 0; j < 2; ++j)
            GLOAD_LDS16(A + (long)(m0 + ra[j]) * K + kk + ca[j],
                        As + (wave * 128 + j * 64) * 8);
        #pragma unroll
        for (int j = 0; j < BN_ / 64; ++j)
            GLOAD_LDS16(Bt + (long)(n0 + rb[j]) * K + kk + cb_[j],
                        Bs + (wave * BN_ + j * 64) * 8);
        __syncthreads();

        f16x8 af[4], bf[NI];
        #pragma unroll
        for (int mi = 0; mi < 4; ++mi)
            af[mi] = *(const f16x8*)(As + (wm * 64 + mi * 16 + lrow) * BK + qoff);
        #pragma unroll
        for (int ni = 0; ni < NI; ++ni)
            bf[ni] = *(const f16x8*)(Bs + (wn * (BN_ / 2) + ni * 16 + lrow) * BK + qoff);
        #pragma unroll
        for (int mi = 0; mi < 4; ++mi)
            #pragma unroll
            for (int ni = 0; ni < NI; ++ni)
                acc[mi][ni] = __builtin_amdgcn_mfma_f32_16x16x32_f16(af[mi], bf[ni], acc[mi][ni], 0, 0, 0);
        __syncthreads();
    }

    CT* Cz = C + (long)blockIdx.z * M * N;
    #pragma unroll
    for (int mi = 0; mi < 4; ++mi) {
        #pragma unroll
        for (int ni = 0; ni < NI; ++ni) {
            int col = n0 + wn * (BN_ / 2) + ni * 16 + lrow;
            if (col < N) {
                #pragma unroll
                for (int r = 0; r < 4; ++r) {
                    int row = m0 + wm * 64 + mi * 16 + quad * 4 + r;
                    Cz[(long)row * N + col] = (CT)acc[mi][ni][r];
                }
            }
        }
    }
}

// ---------------------------------------------------------------------------
// x_proj split-K reduce: sum 8 partial slabs (L,256), write ssm (L,160) f32
// and dt_in (L,128) f16 in one pass.
__global__ void xproj_reduce_kernel(const float* __restrict__ part, float* __restrict__ ssm,
                                    _Float16* __restrict__ dtin) {
    int idx = blockIdx.x * 256 + threadIdx.x;
    if (idx >= LSEQ * GDIM) return;
    int t = idx / GDIM;
    int c = idx - t * GDIM;
    float v = 0.f;
    #pragma unroll
    for (int k = 0; k < 8; ++k)
        v += part[((long)k * LSEQ + t) * 256 + c];
    ssm[idx] = v;
    if (c < RRANK) dtin[t * RRANK + c] = (_Float16)v;
}

// ---------------------------------------------------------------------------
// depthwise causal conv (K=4) + bias + SiLU, 8 channels/thread vectorized
__global__ void conv_silu_kernel(const _Float16* __restrict__ proj, const float* __restrict__ w,
                                 const float* __restrict__ b, _Float16* __restrict__ u16) {
    int idx = blockIdx.x * 256 + threadIdx.x;   // L * I/8
    int i0 = (idx & 511) * 8;
    int t = idx >> 9;
    const long rowbase = (long)t * (2 * IDIM) + i0;
    f16x8 x0, xm1 = {0,0,0,0,0,0,0,0}, xm2 = {0,0,0,0,0,0,0,0}, xm3 = {0,0,0,0,0,0,0,0};
    x0 = *(const f16x8*)(proj + rowbase);
    if (t >= 1) xm1 = *(const f16x8*)(proj + rowbase - 1 * 2 * IDIM);
    if (t >= 2) xm2 = *(const f16x8*)(proj + rowbase - 2 * 2 * IDIM);
    if (t >= 3) xm3 = *(const f16x8*)(proj + rowbase - 3 * 2 * IDIM);
    f16x8 res;
    #pragma unroll
    for (int j = 0; j < 8; ++j) {
        float4 wv = ((const float4*)w)[i0 + j];
        float a = b[i0 + j]
                + (float)xm3[j] * wv.x + (float)xm2[j] * wv.y
                + (float)xm1[j] * wv.z + (float)x0[j] * wv.w;
        res[j] = (_Float16)(a / (1.f + __expf(-a)));
    }
    *(f16x8*)(u16 + (long)t * IDIM + i0) = res;
}

// ---------------------------------------------------------------------------
__device__ __forceinline__ float softplus_f(float x) {
    if (x > 20.f) return x;
    return log1pf(__expf(x));
}
__device__ __forceinline__ float silu_f(float x) {
    return x / (1.f + __expf(-x));
}

// ---------------------------------------------------------------------------
// Chunked selective scan. One thread per channel i, 16 states in registers.
__global__ __launch_bounds__(256)
void scan_pass1_kernel(const float* __restrict__ dtlin, const float* __restrict__ dtb,
                       const float* __restrict__ ssm, const _Float16* __restrict__ u16,
                       const float* __restrict__ A_log,
                       float* __restrict__ Pc, float* __restrict__ Sc) {
    const int c = blockIdx.y;
    const int i = blockIdx.x * 256 + threadIdx.x;

    __shared__ float Bs[TCHUNK * 16];
    for (int idx = threadIdx.x; idx < TCHUNK * 16; idx += 256) {
        int t = idx >> 4, n = idx & 15;
        Bs[idx] = ssm[(c * TCHUNK + t) * GDIM + RRANK + n];
    }
    __syncthreads();

    float A[16];
    {
        const float4* Ap = (const float4*)(A_log + i * 16);
        #pragma unroll
        for (int q = 0; q < 4; ++q) {
            float4 v = Ap[q];
            A[q * 4 + 0] = -__expf(v.x);
            A[q * 4 + 1] = -__expf(v.y);
            A[q * 4 + 2] = -__expf(v.z);
            A[q * 4 + 3] = -__expf(v.w);
        }
    }
    const float dtbi = dtb[i];

    float s[16], p[16];
    #pragma unroll
    for (int n = 0; n < 16; ++n) { s[n] = 0.f; p[n] = 1.f; }

    long base = (long)c * TCHUNK * IDIM + i;
    for (int t = 0; t < TCHUNK; ++t) {
        float dt = softplus_f(dtlin[base + (long)t * IDIM] + dtbi);
        float dtu = dt * (float)u16[base + (long)t * IDIM];
        #pragma unroll
        for (int n = 0; n < 16; ++n) {
            float dA = __expf(dt * A[n]);
            s[n] = s[n] * dA + dtu * Bs[t * 16 + n];
            p[n] *= dA;
        }
    }

    long o = ((long)c * IDIM + i) * 16;
    #pragma unroll
    for (int q = 0; q < 4; ++q) {
        *(float4*)(Pc + o + q * 4) = make_float4(p[q*4+0], p[q*4+1], p[q*4+2], p[q*4+3]);
        *(float4*)(Sc + o + q * 4) = make_float4(s[q*4+0], s[q*4+1], s[q*4+2], s[q*4+3]);
    }
}

__global__ void scan_combine_kernel(const float* __restrict__ Pc, float* __restrict__ ScInit) {
    int tid = blockIdx.x * 256 + threadIdx.x;   // I*16
    float carry = 0.f;
    for (int c = 0; c < GCHUNK; ++c) {
        long o = (long)c * (IDIM * 16) + tid;
        float pv = Pc[o];
        float sv = ScInit[o];
        ScInit[o] = carry;
        carry = carry * pv + sv;
    }
}

__global__ __launch_bounds__(256)
void scan_pass3_kernel(const float* __restrict__ dtlin, const float* __restrict__ dtb,
                       const float* __restrict__ ssm, const _Float16* __restrict__ u16,
                       const _Float16* __restrict__ proj, const float* __restrict__ A_log,
                       const float* __restrict__ Dp, const float* __restrict__ Init,
                       _Float16* __restrict__ y16) {
    const int c = blockIdx.y;
    const int i = blockIdx.x * 256 + threadIdx.x;

    __shared__ float Bs[TCHUNK * 16];
    __shared__ float Cs[TCHUNK * 16];
    for (int idx = threadIdx.x; idx < TCHUNK * 16; idx += 256) {
        int t = idx >> 4, n = idx & 15;
        Bs[idx] = ssm[(c * TCHUNK + t) * GDIM + RRANK + n];
        Cs[idx] = ssm[(c * TCHUNK + t) * GDIM + RRANK + NSTATE + n];
    }
    __syncthreads();

    float A[16];
    {
        const float4* Ap = (const float4*)(A_log + i * 16);
        #pragma unroll
        for (int q = 0; q < 4; ++q) {
            float4 v = Ap[q];
            A[q * 4 + 0] = -__expf(v.x);
            A[q * 4 + 1] = -__expf(v.y);
            A[q * 4 + 2] = -__expf(v.z);
            A[q * 4 + 3] = -__expf(v.w);
        }
    }
    const float dtbi = dtb[i];
    const float Dv = Dp[i];

    float s[16];
    {
        long o = ((long)c * IDIM + i) * 16;
        #pragma unroll
        for (int q = 0; q < 4; ++q) {
            float4 v = *(const float4*)(Init + o + q * 4);
            s[q*4+0] = v.x; s[q*4+1] = v.y; s[q*4+2] = v.z; s[q*4+3] = v.w;
        }
    }

    long base = (long)c * TCHUNK * IDIM + i;
    for (int t = 0; t < TCHUNK; ++t) {
        float dt = softplus_f(dtlin[base + (long)t * IDIM] + dtbi);
        float uv = (float)u16[base + (long)t * IDIM];
        float dtu = dt * uv;
        float y = 0.f;
        #pragma unroll
        for (int n = 0; n < 16; ++n) {
            float dA = __expf(dt * A[n]);
            s[n] = s[n] * dA + dtu * Bs[t * 16 + n];
            y += s[n] * Cs[t * 16 + n];
        }
        int tg = c * TCHUNK + t;
        float g = (float)proj[(long)tg * (2 * IDIM) + IDIM + i];
        float out = (y + uv * Dv) * silu_f(g);
        y16[base + (long)t * IDIM] = (_Float16)out;
    }
}

// ---------------------------------------------------------------------------
extern "C" void kernel_launch(void* const* d_in, const int* in_sizes, int n_in,
                              void* d_out, int out_size, void* d_ws, size_t ws_size,
                              hipStream_t stream) {
    const float* x_in  = (const float*)d_in[0];
    const float* w_in  = (const float*)d_in[1];
    const float* cw    = (const float*)d_in[2];
    const float* cb    = (const float*)d_in[3];
    const float* xw    = (const float*)d_in[4];
    const float* dtw   = (const float*)d_in[5];
    const float* dtb   = (const float*)d_in[6];
    const float* alog  = (const float*)d_in[7];
    const float* Dp    = (const float*)d_in[8];
    const float* ow    = (const float*)d_in[9];
    float* out = (float*)d_out;

    char* p = (char*)d_ws;
    auto alloc = [&](size_t bytes) { char* r = p; p += (bytes + 255) & ~255ull; return r; };
    _Float16* Xf    = (_Float16*)alloc((size_t)LSEQ * HID * 2);
    _Float16* Wt1   = (_Float16*)alloc((size_t)2 * IDIM * HID * 2);      // (2I, H); dead after in_proj
    _Float16* proj  = (_Float16*)alloc((size_t)LSEQ * 2 * IDIM * 2);
    _Float16* u16   = (_Float16*)alloc((size_t)LSEQ * IDIM * 2);
    _Float16* Wt2   = (_Float16*)alloc((size_t)256 * IDIM * 2);          // (GDIM pad 256, I)
    float*    ssm   = (float*)alloc((size_t)LSEQ * GDIM * 4);
    _Float16* dtin  = (_Float16*)alloc((size_t)LSEQ * RRANK * 2);
    _Float16* Wt3   = (_Float16*)alloc((size_t)IDIM * RRANK * 2);        // (I, R)
    float*    dtlin = (float*)alloc((size_t)LSEQ * IDIM * 4);
    _Float16* Wt4   = (_Float16*)alloc((size_t)HID * IDIM * 2);          // (H, I)
    _Float16* y16   = (_Float16*)alloc((size_t)LSEQ * IDIM * 2);

    // aliases into dead Wt1 region (33.5 MB):
    float* xpart = (float*)Wt1;                       // 8 x 2048 x 256 f32 = 16.8 MB (dead after reduce)
    float* Pc = (float*)Wt1;                          // G*I*16 f32 = 16.8 MB (written after xpart dead)
    float* Sc = Pc + (size_t)GCHUNK * IDIM * 16;      // G*I*16 f32 = 16.8 MB

    f32_to_f16_kernel<<<(LSEQ * HID) / 256, 256, 0, stream>>>(x_in, Xf, LSEQ * HID);
    transpose_f32_f16_kernel<<<dim3(2 * IDIM / 32, HID / 32), 256, 0, stream>>>(w_in, Wt1, HID, 2 * IDIM);
    transpose_f32_f16_kernel<<<dim3(GDIM / 32, IDIM / 32), 256, 0, stream>>>(xw, Wt2, IDIM, GDIM);
    transpose_f32_f16_kernel<<<dim3(IDIM / 32, RRANK / 32), 256, 0, stream>>>(dtw, Wt3, RRANK, IDIM);
    transpose_f32_f16_kernel<<<dim3(HID / 32, IDIM / 32), 256, 0, stream>>>(ow, Wt4, IDIM, HID);

    // in_proj: (L,H)@(H,2I) -> proj f16
    gemm_bt_kernel<_Float16, 128><<<dim3(2 * IDIM / 128, LSEQ / BM, 1), 256, 0, stream>>>(
        Xf, Wt1, proj, LSEQ, 2 * IDIM, HID, HID);
    // conv + SiLU -> u16
    conv_silu_kernel<<<(LSEQ * IDIM / 8) / 256, 256, 0, stream>>>(proj, cw, cb, u16);
    // x_proj split-K x8: (L,I)@(I,256pad) -> partials
    gemm_bt_kernel<float, 128><<<dim3(2, LSEQ / BM, 8), 256, 0, stream>>>(
        u16, Wt2, xpart, LSEQ, 256, IDIM, IDIM / 8);
    xproj_reduce_kernel<<<(LSEQ * GDIM + 255) / 256, 256, 0, stream>>>(xpart, ssm, dtin);
    // dt_proj: (L,R)@(R,I) -> dtlin f32
    gemm_bt_kernel<float, 128><<<dim3(IDIM / 128, LSEQ / BM, 1), 256, 0, stream>>>(
        dtin, Wt3, dtlin, LSEQ, IDIM, RRANK, RRANK);
    // chunked scan
    scan_pass1_kernel<<<dim3(IDIM / 256, GCHUNK), 256, 0, stream>>>(
        dtlin, dtb, ssm, u16, alog, Pc, Sc);
    scan_combine_kernel<<<(IDIM * NSTATE) / 256, 256, 0, stream>>>(Pc, Sc);
    scan_pass3_kernel<<<dim3(IDIM / 256, GCHUNK), 256, 0, stream>>>(
        dtlin, dtb, ssm, u16, proj, alog, Dp, Sc, y16);
    // out_proj: (L,I)@(I,H) -> out f32, BN=64 for 512 blocks (2/CU latency overlap)
    gemm_bt_kernel<float, 64><<<dim3(HID / 64, LSEQ / BM, 1), 256, 0, stream>>>(
        y16, Wt4, out, LSEQ, HID, IDIM, IDIM);
}

// Round 4
// 519.664 us; speedup vs baseline: 5.5741x; 1.0634x over previous
//
#include <hip/hip_runtime.h>
#include <stdint.h>

// Mamba-1.4B-like dims (fixed)
#define LSEQ 2048
#define HID  2048
#define IDIM 4096
#define NSTATE 16
#define RRANK 128
#define GDIM 160   // RRANK + 2*NSTATE

// chunked scan
#define GCHUNK 64
#define TCHUNK (LSEQ / GCHUNK)   // 32

typedef _Float16 f16x8 __attribute__((ext_vector_type(8)));
typedef float f32x4 __attribute__((ext_vector_type(4)));

#define GLOAD_LDS16(g, l) __builtin_amdgcn_global_load_lds( \
    (const __attribute__((address_space(1))) void*)(g),     \
    (__attribute__((address_space(3))) void*)(l), 16, 0, 0)

// ---------------------------------------------------------------------------
__global__ void f32_to_f16_kernel(const float* __restrict__ in, _Float16* __restrict__ out, int n) {
    int i = blockIdx.x * 256 + threadIdx.x;
    if (i < n) out[i] = (_Float16)in[i];
}

// ---------------------------------------------------------------------------
// transpose f32 (R x C) -> f16 (C x R)
__global__ void transpose_f32_f16_kernel(const float* __restrict__ in, _Float16* __restrict__ out,
                                         int R, int C) {
    __shared__ float tile[32][33];
    int bx = blockIdx.x;
    int by = blockIdx.y;
    int tx = threadIdx.x & 31;
    int ty = threadIdx.x >> 5;
    int r0 = by * 32, c0 = bx * 32;
    #pragma unroll
    for (int j = 0; j < 32; j += 8)
        tile[ty + j][tx] = in[(long)(r0 + ty + j) * C + c0 + tx];
    __syncthreads();
    #pragma unroll
    for (int j = 0; j < 32; j += 8)
        out[(long)(c0 + ty + j) * R + r0 + tx] = (_Float16)tile[tx][ty + j];
}

// ---------------------------------------------------------------------------
// GEMM: C = A(M,K) @ Bt(N,K)^T, fp16 in, fp32 acc. BM=128 fixed, BN_ in {64,128}.
// BK=64: global_load_lds 16B DMA staging; LDS rows of 64 f16 (8 chunks of 16B),
// chunk q of row r stored at slot q^(r&7) -> conflict-free ds_read_b128
// (2-way max, free per m136). K-split via blockIdx.z over [z*kc, z*kc+kc).
#define BM 128
#define BK 64

template <typename CT, int BN_>
__global__ __launch_bounds__(256)
void gemm_bt_kernel(const _Float16* __restrict__ A, const _Float16* __restrict__ Bt,
                    CT* __restrict__ C, int M, int N, int K, int kc) {
    constexpr int NI = BN_ / 32;           // 16-col tiles per wave
    constexpr int NISS_B = BN_ * 8 / 256;  // B staging issues per thread
    __shared__ _Float16 As[BM * BK];
    __shared__ _Float16 Bs[BN_ * BK];
    const int m0 = blockIdx.y * BM;
    const int n0 = blockIdx.x * BN_;
    const int t = threadIdx.x;
    const int wave = t >> 6;
    const int lane = t & 63;
    const int wm = wave >> 1, wn = wave & 1;
    const int lrow = lane & 15;
    const int quad = lane >> 4;
    const int sw8 = (lrow & 7) * 8;        // fragment-read XOR (in elements)

    f32x4 acc[4][NI];
    #pragma unroll
    for (int mi = 0; mi < 4; ++mi)
        #pragma unroll
        for (int ni = 0; ni < NI; ++ni)
            #pragma unroll
            for (int r = 0; r < 4; ++r)
                acc[mi][ni][r] = 0.f;

    // staging source offsets (elements); slot s = j*256 + t, row = s>>3,
    // global chunk = (s&7) ^ (row&7)
    long gA[4];
    #pragma unroll
    for (int j = 0; j < 4; ++j) {
        int s = j * 256 + t;
        int row = s >> 3;
        int ch = (s & 7) ^ (row & 7);
        gA[j] = (long)(m0 + row) * K + ch * 8;
    }
    long gB[NISS_B];
    #pragma unroll
    for (int j = 0; j < NISS_B; ++j) {
        int s = j * 256 + t;
        int row = s >> 3;
        int ch = (s & 7) ^ (row & 7);
        gB[j] = (long)(n0 + row) * K + ch * 8;
    }

    const int k_begin = blockIdx.z * kc;
    const int k_end = k_begin + kc;

    for (int kk = k_begin; kk < k_end; kk += BK) {
        #pragma unroll
        for (int j = 0; j < 4; ++j)
            GLOAD_LDS16(A + gA[j] + kk, As + (j * 256 + wave * 64) * 8);
        #pragma unroll
        for (int j = 0; j < NISS_B; ++j)
            GLOAD_LDS16(Bt + gB[j] + kk, Bs + (j * 256 + wave * 64) * 8);
        __syncthreads();

        #pragma unroll
        for (int h = 0; h < 2; ++h) {
            const int qoff = (h * 32 + quad * 8) ^ sw8;
            f16x8 af[4], bf[NI];
            #pragma unroll
            for (int mi = 0; mi < 4; ++mi)
                af[mi] = *(const f16x8*)(As + (wm * 64 + mi * 16 + lrow) * BK + qoff);
            #pragma unroll
            for (int ni = 0; ni < NI; ++ni)
                bf[ni] = *(const f16x8*)(Bs + (wn * (BN_ / 2) + ni * 16 + lrow) * BK + qoff);
            #pragma unroll
            for (int mi = 0; mi < 4; ++mi)
                #pragma unroll
                for (int ni = 0; ni < NI; ++ni)
                    acc[mi][ni] = __builtin_amdgcn_mfma_f32_16x16x32_f16(af[mi], bf[ni], acc[mi][ni], 0, 0, 0);
        }
        __syncthreads();
    }

    CT* Cz = C + (long)blockIdx.z * M * N;
    #pragma unroll
    for (int mi = 0; mi < 4; ++mi) {
        #pragma unroll
        for (int ni = 0; ni < NI; ++ni) {
            int col = n0 + wn * (BN_ / 2) + ni * 16 + lrow;
            if (col < N) {
                #pragma unroll
                for (int r = 0; r < 4; ++r) {
                    int row = m0 + wm * 64 + mi * 16 + quad * 4 + r;
                    Cz[(long)row * N + col] = (CT)acc[mi][ni][r];
                }
            }
        }
    }
}

// ---------------------------------------------------------------------------
// x_proj split-K reduce: sum 8 partial slabs (L,256), write ssm (L,160) f32
// and dt_in (L,128) f16 in one pass.
__global__ void xproj_reduce_kernel(const float* __restrict__ part, float* __restrict__ ssm,
                                    _Float16* __restrict__ dtin) {
    int idx = blockIdx.x * 256 + threadIdx.x;
    if (idx >= LSEQ * GDIM) return;
    int t = idx / GDIM;
    int c = idx - t * GDIM;
    float v = 0.f;
    #pragma unroll
    for (int k = 0; k < 8; ++k)
        v += part[((long)k * LSEQ + t) * 256 + c];
    ssm[idx] = v;
    if (c < RRANK) dtin[t * RRANK + c] = (_Float16)v;
}

// ---------------------------------------------------------------------------
// depthwise causal conv (K=4) + bias + SiLU; 8 channels x 4 timesteps/thread
// (7 row-loads instead of 16).
__global__ void conv_silu_kernel(const _Float16* __restrict__ proj, const float* __restrict__ w,
                                 const float* __restrict__ b, _Float16* __restrict__ u16) {
    int idx = blockIdx.x * 256 + threadIdx.x;   // (L/4) * (I/8)
    int i0 = (idx & 511) * 8;
    int t0 = (idx >> 9) * 4;
    f16x8 r[7];
    #pragma unroll
    for (int k = 0; k < 7; ++k) {
        int tt = t0 - 3 + k;
        if (tt >= 0) r[k] = *(const f16x8*)(proj + (long)tt * (2 * IDIM) + i0);
        else         r[k] = f16x8{0,0,0,0,0,0,0,0};
    }
    float4 wv[8]; float bb[8];
    #pragma unroll
    for (int j = 0; j < 8; ++j) { wv[j] = ((const float4*)w)[i0 + j]; bb[j] = b[i0 + j]; }
    #pragma unroll
    for (int tt = 0; tt < 4; ++tt) {
        f16x8 res;
        #pragma unroll
        for (int j = 0; j < 8; ++j) {
            float a = bb[j] + (float)r[tt][j] * wv[j].x + (float)r[tt+1][j] * wv[j].y
                            + (float)r[tt+2][j] * wv[j].z + (float)r[tt+3][j] * wv[j].w;
            res[j] = (_Float16)(a / (1.f + __expf(-a)));
        }
        *(f16x8*)(u16 + (long)(t0 + tt) * IDIM + i0) = res;
    }
}

// ---------------------------------------------------------------------------
__device__ __forceinline__ float softplus_f(float x) {
    if (x > 20.f) return x;
    return log1pf(__expf(x));
}
__device__ __forceinline__ float silu_f(float x) {
    return x / (1.f + __expf(-x));
}

// ---------------------------------------------------------------------------
// Chunked selective scan. One thread per channel i, 16 states in registers.
__global__ __launch_bounds__(256)
void scan_pass1_kernel(const _Float16* __restrict__ dtlin, const float* __restrict__ dtb,
                       const float* __restrict__ ssm, const _Float16* __restrict__ u16,
                       const float* __restrict__ A_log,
                       float* __restrict__ Pc, float* __restrict__ Sc) {
    const int c = blockIdx.y;
    const int i = blockIdx.x * 256 + threadIdx.x;

    __shared__ float Bs[TCHUNK * 16];
    for (int idx = threadIdx.x; idx < TCHUNK * 16; idx += 256) {
        int t = idx >> 4, n = idx & 15;
        Bs[idx] = ssm[(c * TCHUNK + t) * GDIM + RRANK + n];
    }
    __syncthreads();

    float A[16];
    {
        const float4* Ap = (const float4*)(A_log + i * 16);
        #pragma unroll
        for (int q = 0; q < 4; ++q) {
            float4 v = Ap[q];
            A[q * 4 + 0] = -__expf(v.x);
            A[q * 4 + 1] = -__expf(v.y);
            A[q * 4 + 2] = -__expf(v.z);
            A[q * 4 + 3] = -__expf(v.w);
        }
    }
    const float dtbi = dtb[i];

    float s[16], p[16];
    #pragma unroll
    for (int n = 0; n < 16; ++n) { s[n] = 0.f; p[n] = 1.f; }

    long base = (long)c * TCHUNK * IDIM + i;
    for (int t = 0; t < TCHUNK; ++t) {
        float dt = softplus_f((float)dtlin[base + (long)t * IDIM] + dtbi);
        float dtu = dt * (float)u16[base + (long)t * IDIM];
        #pragma unroll
        for (int n = 0; n < 16; ++n) {
            float dA = __expf(dt * A[n]);
            s[n] = s[n] * dA + dtu * Bs[t * 16 + n];
            p[n] *= dA;
        }
    }

    long o = ((long)c * IDIM + i) * 16;
    #pragma unroll
    for (int q = 0; q < 4; ++q) {
        *(float4*)(Pc + o + q * 4) = make_float4(p[q*4+0], p[q*4+1], p[q*4+2], p[q*4+3]);
        *(float4*)(Sc + o + q * 4) = make_float4(s[q*4+0], s[q*4+1], s[q*4+2], s[q*4+3]);
    }
}

// Combine: sequential over G chunks per (i,n); group-of-4 prefetch to overlap
// HBM latency with the (tiny) carry chain. Init overwrites Sc in place.
__global__ void scan_combine_kernel(const float* __restrict__ Pc, float* __restrict__ ScInit) {
    int tid = blockIdx.x * 256 + threadIdx.x;   // I*16
    const long stride = (long)IDIM * 16;
    float p4[4], s4[4];
    #pragma unroll
    for (int k = 0; k < 4; ++k) {
        p4[k] = Pc[(long)k * stride + tid];
        s4[k] = ScInit[(long)k * stride + tid];
    }
    float carry = 0.f;
    for (int g = 0; g < GCHUNK / 4; ++g) {
        float pc[4], sc[4];
        #pragma unroll
        for (int k = 0; k < 4; ++k) { pc[k] = p4[k]; sc[k] = s4[k]; }
        if (g + 1 < GCHUNK / 4) {
            #pragma unroll
            for (int k = 0; k < 4; ++k) {
                long o2 = (long)((g + 1) * 4 + k) * stride + tid;
                p4[k] = Pc[o2];
                s4[k] = ScInit[o2];
            }
        }
        #pragma unroll
        for (int k = 0; k < 4; ++k) {
            long o = (long)(g * 4 + k) * stride + tid;
            ScInit[o] = carry;
            carry = carry * pc[k] + sc[k];
        }
    }
}

__global__ __launch_bounds__(256)
void scan_pass3_kernel(const _Float16* __restrict__ dtlin, const float* __restrict__ dtb,
                       const float* __restrict__ ssm, const _Float16* __restrict__ u16,
                       const _Float16* __restrict__ proj, const float* __restrict__ A_log,
                       const float* __restrict__ Dp, const float* __restrict__ Init,
                       _Float16* __restrict__ y16) {
    const int c = blockIdx.y;
    const int i = blockIdx.x * 256 + threadIdx.x;

    __shared__ float Bs[TCHUNK * 16];
    __shared__ float Cs[TCHUNK * 16];
    for (int idx = threadIdx.x; idx < TCHUNK * 16; idx += 256) {
        int t = idx >> 4, n = idx & 15;
        Bs[idx] = ssm[(c * TCHUNK + t) * GDIM + RRANK + n];
        Cs[idx] = ssm[(c * TCHUNK + t) * GDIM + RRANK + NSTATE + n];
    }
    __syncthreads();

    float A[16];
    {
        const float4* Ap = (const float4*)(A_log + i * 16);
        #pragma unroll
        for (int q = 0; q < 4; ++q) {
            float4 v = Ap[q];
            A[q * 4 + 0] = -__expf(v.x);
            A[q * 4 + 1] = -__expf(v.y);
            A[q * 4 + 2] = -__expf(v.z);
            A[q * 4 + 3] = -__expf(v.w);
        }
    }
    const float dtbi = dtb[i];
    const float Dv = Dp[i];

    float s[16];
    {
        long o = ((long)c * IDIM + i) * 16;
        #pragma unroll
        for (int q = 0; q < 4; ++q) {
            float4 v = *(const float4*)(Init + o + q * 4);
            s[q*4+0] = v.x; s[q*4+1] = v.y; s[q*4+2] = v.z; s[q*4+3] = v.w;
        }
    }

    long base = (long)c * TCHUNK * IDIM + i;
    for (int t = 0; t < TCHUNK; ++t) {
        float dt = softplus_f((float)dtlin[base + (long)t * IDIM] + dtbi);
        float uv = (float)u16[base + (long)t * IDIM];
        float dtu = dt * uv;
        float y = 0.f;
        #pragma unroll
        for (int n = 0; n < 16; ++n) {
            float dA = __expf(dt * A[n]);
            s[n] = s[n] * dA + dtu * Bs[t * 16 + n];
            y += s[n] * Cs[t * 16 + n];
        }
        int tg = c * TCHUNK + t;
        float g = (float)proj[(long)tg * (2 * IDIM) + IDIM + i];
        float out = (y + uv * Dv) * silu_f(g);
        y16[base + (long)t * IDIM] = (_Float16)out;
    }
}

// ---------------------------------------------------------------------------
extern "C" void kernel_launch(void* const* d_in, const int* in_sizes, int n_in,
                              void* d_out, int out_size, void* d_ws, size_t ws_size,
                              hipStream_t stream) {
    const float* x_in  = (const float*)d_in[0];
    const float* w_in  = (const float*)d_in[1];
    const float* cw    = (const float*)d_in[2];
    const float* cb    = (const float*)d_in[3];
    const float* xw    = (const float*)d_in[4];
    const float* dtw   = (const float*)d_in[5];
    const float* dtb   = (const float*)d_in[6];
    const float* alog  = (const float*)d_in[7];
    const float* Dp    = (const float*)d_in[8];
    const float* ow    = (const float*)d_in[9];
    float* out = (float*)d_out;

    char* p = (char*)d_ws;
    auto alloc = [&](size_t bytes) { char* r = p; p += (bytes + 255) & ~255ull; return r; };
    _Float16* Xf    = (_Float16*)alloc((size_t)LSEQ * HID * 2);
    _Float16* Wt1   = (_Float16*)alloc((size_t)2 * IDIM * HID * 2);      // (2I, H); dead after in_proj
    _Float16* proj  = (_Float16*)alloc((size_t)LSEQ * 2 * IDIM * 2);
    _Float16* u16   = (_Float16*)alloc((size_t)LSEQ * IDIM * 2);
    _Float16* Wt2   = (_Float16*)alloc((size_t)256 * IDIM * 2);          // (GDIM pad 256, I)
    float*    ssm   = (float*)alloc((size_t)LSEQ * GDIM * 4);
    _Float16* dtin  = (_Float16*)alloc((size_t)LSEQ * RRANK * 2);
    _Float16* Wt3   = (_Float16*)alloc((size_t)IDIM * RRANK * 2);        // (I, R)
    _Float16* dtlin = (_Float16*)alloc((size_t)LSEQ * IDIM * 2);         // f16 now
    _Float16* Wt4   = (_Float16*)alloc((size_t)HID * IDIM * 2);          // (H, I)
    _Float16* y16   = (_Float16*)alloc((size_t)LSEQ * IDIM * 2);

    // aliases into dead Wt1 region (33.5 MB):
    float* xpart = (float*)Wt1;                       // 8 x 2048 x 256 f32 (dead after reduce)
    float* Pc = (float*)Wt1;                          // G*I*16 f32 (written after xpart dead)
    float* Sc = Pc + (size_t)GCHUNK * IDIM * 16;

    f32_to_f16_kernel<<<(LSEQ * HID) / 256, 256, 0, stream>>>(x_in, Xf, LSEQ * HID);
    transpose_f32_f16_kernel<<<dim3(2 * IDIM / 32, HID / 32), 256, 0, stream>>>(w_in, Wt1, HID, 2 * IDIM);
    transpose_f32_f16_kernel<<<dim3(GDIM / 32, IDIM / 32), 256, 0, stream>>>(xw, Wt2, IDIM, GDIM);
    transpose_f32_f16_kernel<<<dim3(IDIM / 32, RRANK / 32), 256, 0, stream>>>(dtw, Wt3, RRANK, IDIM);
    transpose_f32_f16_kernel<<<dim3(HID / 32, IDIM / 32), 256, 0, stream>>>(ow, Wt4, IDIM, HID);

    // in_proj: (L,H)@(H,2I) -> proj f16
    gemm_bt_kernel<_Float16, 128><<<dim3(2 * IDIM / 128, LSEQ / BM, 1), 256, 0, stream>>>(
        Xf, Wt1, proj, LSEQ, 2 * IDIM, HID, HID);
    // conv + SiLU -> u16
    conv_silu_kernel<<<(LSEQ / 4) * (IDIM / 8) / 256, 256, 0, stream>>>(proj, cw, cb, u16);
    // x_proj split-K x8: (L,I)@(I,256pad) -> partials
    gemm_bt_kernel<float, 128><<<dim3(2, LSEQ / BM, 8), 256, 0, stream>>>(
        u16, Wt2, xpart, LSEQ, 256, IDIM, IDIM / 8);
    xproj_reduce_kernel<<<(LSEQ * GDIM + 255) / 256, 256, 0, stream>>>(xpart, ssm, dtin);
    // dt_proj: (L,R)@(R,I) -> dtlin f16
    gemm_bt_kernel<_Float16, 128><<<dim3(IDIM / 128, LSEQ / BM, 1), 256, 0, stream>>>(
        dtin, Wt3, dtlin, LSEQ, IDIM, RRANK, RRANK);
    // chunked scan
    scan_pass1_kernel<<<dim3(IDIM / 256, GCHUNK), 256, 0, stream>>>(
        dtlin, dtb, ssm, u16, alog, Pc, Sc);
    scan_combine_kernel<<<(IDIM * NSTATE) / 256, 256, 0, stream>>>(Pc, Sc);
    scan_pass3_kernel<<<dim3(IDIM / 256, GCHUNK), 256, 0, stream>>>(
        dtlin, dtb, ssm, u16, proj, alog, Dp, Sc, y16);
    // out_proj: (L,I)@(I,H) -> out f32, BN=64 for 512 blocks
    gemm_bt_kernel<float, 64><<<dim3(HID / 64, LSEQ / BM, 1), 256, 0, stream>>>(
        y16, Wt4, out, LSEQ, HID, IDIM, IDIM);
}

// Round 5
// 502.088 us; speedup vs baseline: 5.7692x; 1.0350x over previous
//
#include <hip/hip_runtime.h>
#include <stdint.h>

// Mamba-1.4B-like dims (fixed)
#define LSEQ 2048
#define HID  2048
#define IDIM 4096
#define NSTATE 16
#define RRANK 128
#define GDIM 160   // RRANK + 2*NSTATE

// chunked scan
#define GCHUNK 64
#define TCHUNK (LSEQ / GCHUNK)   // 32

typedef _Float16 f16x8 __attribute__((ext_vector_type(8)));
typedef float f32x4 __attribute__((ext_vector_type(4)));

#define GLOAD_LDS16(g, l) __builtin_amdgcn_global_load_lds( \
    (const __attribute__((address_space(1))) void*)(g),     \
    (__attribute__((address_space(3))) void*)(l), 16, 0, 0)

// ---------------------------------------------------------------------------
__global__ void f32_to_f16_kernel(const float* __restrict__ in, _Float16* __restrict__ out, int n) {
    int i = blockIdx.x * 256 + threadIdx.x;
    if (i < n) out[i] = (_Float16)in[i];
}

// ---------------------------------------------------------------------------
// transpose f32 (R x C) -> f16 (C x R); 64x64 tiles, float4 loads, f16x8 stores.
// grid = (tiles_c, tiles_r). Partial tiles take the guarded slow path.
__global__ __launch_bounds__(256)
void transpose_f32_f16_kernel(const float* __restrict__ in, _Float16* __restrict__ out,
                              int R, int C) {
    __shared__ _Float16 tile[64][66];   // +2 f16 pad: store-gather is 2-way max (free)
    const int c0 = blockIdx.x * 64, r0 = blockIdx.y * 64;
    const int t = threadIdx.x;
    const int tx = t & 15, ty = t >> 4;     // load: 16x16 threads, 4 cols each
    const int ox = t & 7, oy = t >> 3;      // store: 8x32 threads, 8 rows each
    const bool full = (c0 + 64 <= C) && (r0 + 64 <= R);
    if (full) {
        #pragma unroll
        for (int j = 0; j < 4; ++j) {
            int r = ty + j * 16;
            float4 v = *(const float4*)(in + (long)(r0 + r) * C + c0 + tx * 4);
            tile[r][tx * 4 + 0] = (_Float16)v.x;
            tile[r][tx * 4 + 1] = (_Float16)v.y;
            tile[r][tx * 4 + 2] = (_Float16)v.z;
            tile[r][tx * 4 + 3] = (_Float16)v.w;
        }
        __syncthreads();
        #pragma unroll
        for (int j = 0; j < 2; ++j) {
            int c = oy + j * 32;
            f16x8 v;
            #pragma unroll
            for (int e = 0; e < 8; ++e) v[e] = tile[ox * 8 + e][c];
            *(f16x8*)(out + (long)(c0 + c) * R + r0 + ox * 8) = v;
        }
    } else {
        #pragma unroll
        for (int j = 0; j < 4; ++j) {
            int r = ty + j * 16;
            #pragma unroll
            for (int e = 0; e < 4; ++e) {
                int c = c0 + tx * 4 + e;
                float v = (r0 + r < R && c < C) ? in[(long)(r0 + r) * C + c] : 0.f;
                tile[r][tx * 4 + e] = (_Float16)v;
            }
        }
        __syncthreads();
        #pragma unroll
        for (int j = 0; j < 2; ++j) {
            int c = c0 + oy + j * 32;
            if (c < C) {
                #pragma unroll
                for (int e = 0; e < 8; ++e) {
                    int r = r0 + ox * 8 + e;
                    if (r < R) out[(long)c * R + r] = tile[ox * 8 + e][oy + j * 32];
                }
            }
        }
    }
}

// ---------------------------------------------------------------------------
// GEMM: C = A(M,K) @ Bt(N,K)^T, fp16 in, fp32 acc. BM=128 fixed, BN_ in {64,128}.
// BK=64: global_load_lds 16B DMA staging; LDS rows of 64 f16 (8 chunks of 16B),
// chunk q of row r stored at slot q^(r&7) -> conflict-free ds_read_b128.
// K-split via blockIdx.z over [z*kc, z*kc+kc), output slab z.
#define BM 128
#define BK 64

template <typename CT, int BN_>
__global__ __launch_bounds__(256)
void gemm_bt_kernel(const _Float16* __restrict__ A, const _Float16* __restrict__ Bt,
                    CT* __restrict__ C, int M, int N, int K, int kc) {
    constexpr int NI = BN_ / 32;           // 16-col tiles per wave
    constexpr int NISS_B = BN_ * 8 / 256;  // B staging issues per thread
    __shared__ _Float16 As[BM * BK];
    __shared__ _Float16 Bs[BN_ * BK];
    const int m0 = blockIdx.y * BM;
    const int n0 = blockIdx.x * BN_;
    const int t = threadIdx.x;
    const int wave = t >> 6;
    const int lane = t & 63;
    const int wm = wave >> 1, wn = wave & 1;
    const int lrow = lane & 15;
    const int quad = lane >> 4;
    const int sw8 = (lrow & 7) * 8;        // fragment-read XOR (in elements)

    f32x4 acc[4][NI];
    #pragma unroll
    for (int mi = 0; mi < 4; ++mi)
        #pragma unroll
        for (int ni = 0; ni < NI; ++ni)
            #pragma unroll
            for (int r = 0; r < 4; ++r)
                acc[mi][ni][r] = 0.f;

    const int k_begin = blockIdx.z * kc;
    // staging source pointers; slot s = j*256 + t, row = s>>3,
    // global chunk = (s&7) ^ (row&7)
    const _Float16* pA[4];
    #pragma unroll
    for (int j = 0; j < 4; ++j) {
        int s = j * 256 + t;
        int row = s >> 3;
        int ch = (s & 7) ^ (row & 7);
        pA[j] = A + (long)(m0 + row) * K + ch * 8 + k_begin;
    }
    const _Float16* pB[NISS_B];
    #pragma unroll
    for (int j = 0; j < NISS_B; ++j) {
        int s = j * 256 + t;
        int row = s >> 3;
        int ch = (s & 7) ^ (row & 7);
        pB[j] = Bt + (long)(n0 + row) * K + ch * 8 + k_begin;
    }

    for (int kk = 0; kk < kc; kk += BK) {
        #pragma unroll
        for (int j = 0; j < 4; ++j) {
            GLOAD_LDS16(pA[j], As + (j * 256 + wave * 64) * 8);
            pA[j] += BK;
        }
        #pragma unroll
        for (int j = 0; j < NISS_B; ++j) {
            GLOAD_LDS16(pB[j], Bs + (j * 256 + wave * 64) * 8);
            pB[j] += BK;
        }
        __syncthreads();

        #pragma unroll
        for (int h = 0; h < 2; ++h) {
            const int qoff = (h * 32 + quad * 8) ^ sw8;
            f16x8 af[4], bf[NI];
            #pragma unroll
            for (int mi = 0; mi < 4; ++mi)
                af[mi] = *(const f16x8*)(As + (wm * 64 + mi * 16 + lrow) * BK + qoff);
            #pragma unroll
            for (int ni = 0; ni < NI; ++ni)
                bf[ni] = *(const f16x8*)(Bs + (wn * (BN_ / 2) + ni * 16 + lrow) * BK + qoff);
            #pragma unroll
            for (int mi = 0; mi < 4; ++mi)
                #pragma unroll
                for (int ni = 0; ni < NI; ++ni)
                    acc[mi][ni] = __builtin_amdgcn_mfma_f32_16x16x32_f16(af[mi], bf[ni], acc[mi][ni], 0, 0, 0);
        }
        __syncthreads();
    }

    CT* Cz = C + (long)blockIdx.z * M * N;
    #pragma unroll
    for (int mi = 0; mi < 4; ++mi) {
        #pragma unroll
        for (int ni = 0; ni < NI; ++ni) {
            int col = n0 + wn * (BN_ / 2) + ni * 16 + lrow;
            if (col < N) {
                #pragma unroll
                for (int r = 0; r < 4; ++r) {
                    int row = m0 + wm * 64 + mi * 16 + quad * 4 + r;
                    Cz[(long)row * N + col] = (CT)acc[mi][ni][r];
                }
            }
        }
    }
}

// ---------------------------------------------------------------------------
// x_proj split-K reduce: sum 8 partial slabs (L,256), write ssm (L,160) f32
// and dt_in (L,128) f16 in one pass.
__global__ void xproj_reduce_kernel(const float* __restrict__ part, float* __restrict__ ssm,
                                    _Float16* __restrict__ dtin) {
    int idx = blockIdx.x * 256 + threadIdx.x;
    if (idx >= LSEQ * GDIM) return;
    int t = idx / GDIM;
    int c = idx - t * GDIM;
    float v = 0.f;
    #pragma unroll
    for (int k = 0; k < 8; ++k)
        v += part[((long)k * LSEQ + t) * 256 + c];
    ssm[idx] = v;
    if (c < RRANK) dtin[t * RRANK + c] = (_Float16)v;
}

// ---------------------------------------------------------------------------
// out_proj split-K reduce: out = part0 + part1 (f32)
__global__ void opart_reduce_kernel(const float* __restrict__ part, float* __restrict__ out) {
    int idx = blockIdx.x * 256 + threadIdx.x;   // L*H
    out[idx] = part[idx] + part[idx + (long)LSEQ * HID];
}

// ---------------------------------------------------------------------------
// depthwise causal conv (K=4) + bias + SiLU; 8 channels x 4 timesteps/thread
__global__ void conv_silu_kernel(const _Float16* __restrict__ proj, const float* __restrict__ w,
                                 const float* __restrict__ b, _Float16* __restrict__ u16) {
    int idx = blockIdx.x * 256 + threadIdx.x;   // (L/4) * (I/8)
    int i0 = (idx & 511) * 8;
    int t0 = (idx >> 9) * 4;
    f16x8 r[7];
    #pragma unroll
    for (int k = 0; k < 7; ++k) {
        int tt = t0 - 3 + k;
        if (tt >= 0) r[k] = *(const f16x8*)(proj + (long)tt * (2 * IDIM) + i0);
        else         r[k] = f16x8{0,0,0,0,0,0,0,0};
    }
    float4 wv[8]; float bb[8];
    #pragma unroll
    for (int j = 0; j < 8; ++j) { wv[j] = ((const float4*)w)[i0 + j]; bb[j] = b[i0 + j]; }
    #pragma unroll
    for (int tt = 0; tt < 4; ++tt) {
        f16x8 res;
        #pragma unroll
        for (int j = 0; j < 8; ++j) {
            float a = bb[j] + (float)r[tt][j] * wv[j].x + (float)r[tt+1][j] * wv[j].y
                            + (float)r[tt+2][j] * wv[j].z + (float)r[tt+3][j] * wv[j].w;
            res[j] = (_Float16)(a / (1.f + __expf(-a)));
        }
        *(f16x8*)(u16 + (long)(t0 + tt) * IDIM + i0) = res;
    }
}

// ---------------------------------------------------------------------------
__device__ __forceinline__ float softplus_f(float x) {
    if (x > 20.f) return x;
    return log1pf(__expf(x));
}
__device__ __forceinline__ float silu_f(float x) {
    return x / (1.f + __expf(-x));
}

// ---------------------------------------------------------------------------
// Chunked selective scan. One thread per channel i, 16 states in registers.
__global__ __launch_bounds__(256)
void scan_pass1_kernel(const _Float16* __restrict__ dtlin, const float* __restrict__ dtb,
                       const float* __restrict__ ssm, const _Float16* __restrict__ u16,
                       const float* __restrict__ A_log,
                       float* __restrict__ Pc, float* __restrict__ Sc) {
    const int c = blockIdx.y;
    const int i = blockIdx.x * 256 + threadIdx.x;

    __shared__ float Bs[TCHUNK * 16];
    for (int idx = threadIdx.x; idx < TCHUNK * 16; idx += 256) {
        int t = idx >> 4, n = idx & 15;
        Bs[idx] = ssm[(c * TCHUNK + t) * GDIM + RRANK + n];
    }
    __syncthreads();

    float A[16];
    {
        const float4* Ap = (const float4*)(A_log + i * 16);
        #pragma unroll
        for (int q = 0; q < 4; ++q) {
            float4 v = Ap[q];
            A[q * 4 + 0] = -__expf(v.x);
            A[q * 4 + 1] = -__expf(v.y);
            A[q * 4 + 2] = -__expf(v.z);
            A[q * 4 + 3] = -__expf(v.w);
        }
    }
    const float dtbi = dtb[i];

    float s[16], p[16];
    #pragma unroll
    for (int n = 0; n < 16; ++n) { s[n] = 0.f; p[n] = 1.f; }

    long base = (long)c * TCHUNK * IDIM + i;
    for (int t = 0; t < TCHUNK; ++t) {
        float dt = softplus_f((float)dtlin[base + (long)t * IDIM] + dtbi);
        float dtu = dt * (float)u16[base + (long)t * IDIM];
        #pragma unroll
        for (int n = 0; n < 16; ++n) {
            float dA = __expf(dt * A[n]);
            s[n] = s[n] * dA + dtu * Bs[t * 16 + n];
            p[n] *= dA;
        }
    }

    long o = ((long)c * IDIM + i) * 16;
    #pragma unroll
    for (int q = 0; q < 4; ++q) {
        *(float4*)(Pc + o + q * 4) = make_float4(p[q*4+0], p[q*4+1], p[q*4+2], p[q*4+3]);
        *(float4*)(Sc + o + q * 4) = make_float4(s[q*4+0], s[q*4+1], s[q*4+2], s[q*4+3]);
    }
}

// Combine: sequential over G chunks per (i,n); group-of-4 prefetch.
__global__ void scan_combine_kernel(const float* __restrict__ Pc, float* __restrict__ ScInit) {
    int tid = blockIdx.x * 256 + threadIdx.x;   // I*16
    const long stride = (long)IDIM * 16;
    float p4[4], s4[4];
    #pragma unroll
    for (int k = 0; k < 4; ++k) {
        p4[k] = Pc[(long)k * stride + tid];
        s4[k] = ScInit[(long)k * stride + tid];
    }
    float carry = 0.f;
    for (int g = 0; g < GCHUNK / 4; ++g) {
        float pc[4], sc[4];
        #pragma unroll
        for (int k = 0; k < 4; ++k) { pc[k] = p4[k]; sc[k] = s4[k]; }
        if (g + 1 < GCHUNK / 4) {
            #pragma unroll
            for (int k = 0; k < 4; ++k) {
                long o2 = (long)((g + 1) * 4 + k) * stride + tid;
                p4[k] = Pc[o2];
                s4[k] = ScInit[o2];
            }
        }
        #pragma unroll
        for (int k = 0; k < 4; ++k) {
            long o = (long)(g * 4 + k) * stride + tid;
            ScInit[o] = carry;
            carry = carry * pc[k] + sc[k];
        }
    }
}

__global__ __launch_bounds__(256)
void scan_pass3_kernel(const _Float16* __restrict__ dtlin, const float* __restrict__ dtb,
                       const float* __restrict__ ssm, const _Float16* __restrict__ u16,
                       const _Float16* __restrict__ proj, const float* __restrict__ A_log,
                       const float* __restrict__ Dp, const float* __restrict__ Init,
                       _Float16* __restrict__ y16) {
    const int c = blockIdx.y;
    const int i = blockIdx.x * 256 + threadIdx.x;

    __shared__ float Bs[TCHUNK * 16];
    __shared__ float Cs[TCHUNK * 16];
    for (int idx = threadIdx.x; idx < TCHUNK * 16; idx += 256) {
        int t = idx >> 4, n = idx & 15;
        Bs[idx] = ssm[(c * TCHUNK + t) * GDIM + RRANK + n];
        Cs[idx] = ssm[(c * TCHUNK + t) * GDIM + RRANK + NSTATE + n];
    }
    __syncthreads();

    float A[16];
    {
        const float4* Ap = (const float4*)(A_log + i * 16);
        #pragma unroll
        for (int q = 0; q < 4; ++q) {
            float4 v = Ap[q];
            A[q * 4 + 0] = -__expf(v.x);
            A[q * 4 + 1] = -__expf(v.y);
            A[q * 4 + 2] = -__expf(v.z);
            A[q * 4 + 3] = -__expf(v.w);
        }
    }
    const float dtbi = dtb[i];
    const float Dv = Dp[i];

    float s[16];
    {
        long o = ((long)c * IDIM + i) * 16;
        #pragma unroll
        for (int q = 0; q < 4; ++q) {
            float4 v = *(const float4*)(Init + o + q * 4);
            s[q*4+0] = v.x; s[q*4+1] = v.y; s[q*4+2] = v.z; s[q*4+3] = v.w;
        }
    }

    long base = (long)c * TCHUNK * IDIM + i;
    for (int t = 0; t < TCHUNK; ++t) {
        float dt = softplus_f((float)dtlin[base + (long)t * IDIM] + dtbi);
        float uv = (float)u16[base + (long)t * IDIM];
        float dtu = dt * uv;
        float y = 0.f;
        #pragma unroll
        for (int n = 0; n < 16; ++n) {
            float dA = __expf(dt * A[n]);
            s[n] = s[n] * dA + dtu * Bs[t * 16 + n];
            y += s[n] * Cs[t * 16 + n];
        }
        int tg = c * TCHUNK + t;
        float g = (float)proj[(long)tg * (2 * IDIM) + IDIM + i];
        float out = (y + uv * Dv) * silu_f(g);
        y16[base + (long)t * IDIM] = (_Float16)out;
    }
}

// ---------------------------------------------------------------------------
extern "C" void kernel_launch(void* const* d_in, const int* in_sizes, int n_in,
                              void* d_out, int out_size, void* d_ws, size_t ws_size,
                              hipStream_t stream) {
    const float* x_in  = (const float*)d_in[0];
    const float* w_in  = (const float*)d_in[1];
    const float* cw    = (const float*)d_in[2];
    const float* cb    = (const float*)d_in[3];
    const float* xw    = (const float*)d_in[4];
    const float* dtw   = (const float*)d_in[5];
    const float* dtb   = (const float*)d_in[6];
    const float* alog  = (const float*)d_in[7];
    const float* Dp    = (const float*)d_in[8];
    const float* ow    = (const float*)d_in[9];
    float* out = (float*)d_out;

    char* p = (char*)d_ws;
    auto alloc = [&](size_t bytes) { char* r = p; p += (bytes + 255) & ~255ull; return r; };
    _Float16* Xf    = (_Float16*)alloc((size_t)LSEQ * HID * 2);
    _Float16* Wt1   = (_Float16*)alloc((size_t)2 * IDIM * HID * 2);      // (2I, H); dead after in_proj
    _Float16* proj  = (_Float16*)alloc((size_t)LSEQ * 2 * IDIM * 2);
    _Float16* u16   = (_Float16*)alloc((size_t)LSEQ * IDIM * 2);
    _Float16* Wt2   = (_Float16*)alloc((size_t)256 * IDIM * 2);          // (GDIM pad 256, I)
    float*    ssm   = (float*)alloc((size_t)LSEQ * GDIM * 4);
    _Float16* dtin  = (_Float16*)alloc((size_t)LSEQ * RRANK * 2);
    _Float16* Wt3   = (_Float16*)alloc((size_t)IDIM * RRANK * 2);        // (I, R)
    _Float16* dtlin = (_Float16*)alloc((size_t)LSEQ * IDIM * 2);
    _Float16* Wt4   = (_Float16*)alloc((size_t)HID * IDIM * 2);          // (H, I)
    _Float16* y16   = (_Float16*)alloc((size_t)LSEQ * IDIM * 2);

    // aliases into dead Wt1 region (33.5 MB), lifetime-ordered:
    //   xpart (until xproj_reduce) -> Pc/Sc (scan) -> opart (out_proj split-K)
    float* xpart = (float*)Wt1;                       // 8 x 2048 x 256 f32
    float* Pc = (float*)Wt1;                          // G*I*16 f32
    float* Sc = Pc + (size_t)GCHUNK * IDIM * 16;
    float* opart = (float*)Wt1;                       // 2 x L*H f32 = 33.5 MB exactly

    f32_to_f16_kernel<<<(LSEQ * HID) / 256, 256, 0, stream>>>(x_in, Xf, LSEQ * HID);
    transpose_f32_f16_kernel<<<dim3(2 * IDIM / 64, HID / 64), 256, 0, stream>>>(w_in, Wt1, HID, 2 * IDIM);
    transpose_f32_f16_kernel<<<dim3((GDIM + 63) / 64, IDIM / 64), 256, 0, stream>>>(xw, Wt2, IDIM, GDIM);
    transpose_f32_f16_kernel<<<dim3(IDIM / 64, RRANK / 64), 256, 0, stream>>>(dtw, Wt3, RRANK, IDIM);
    transpose_f32_f16_kernel<<<dim3(HID / 64, IDIM / 64), 256, 0, stream>>>(ow, Wt4, IDIM, HID);

    // in_proj: (L,H)@(H,2I) -> proj f16
    gemm_bt_kernel<_Float16, 128><<<dim3(2 * IDIM / 128, LSEQ / BM, 1), 256, 0, stream>>>(
        Xf, Wt1, proj, LSEQ, 2 * IDIM, HID, HID);
    // conv + SiLU -> u16
    conv_silu_kernel<<<(LSEQ / 4) * (IDIM / 8) / 256, 256, 0, stream>>>(proj, cw, cb, u16);
    // x_proj split-K x8: (L,I)@(I,256pad) -> partials
    gemm_bt_kernel<float, 128><<<dim3(2, LSEQ / BM, 8), 256, 0, stream>>>(
        u16, Wt2, xpart, LSEQ, 256, IDIM, IDIM / 8);
    xproj_reduce_kernel<<<(LSEQ * GDIM + 255) / 256, 256, 0, stream>>>(xpart, ssm, dtin);
    // dt_proj: (L,R)@(R,I) -> dtlin f16
    gemm_bt_kernel<_Float16, 128><<<dim3(IDIM / 128, LSEQ / BM, 1), 256, 0, stream>>>(
        dtin, Wt3, dtlin, LSEQ, IDIM, RRANK, RRANK);
    // chunked scan
    scan_pass1_kernel<<<dim3(IDIM / 256, GCHUNK), 256, 0, stream>>>(
        dtlin, dtb, ssm, u16, alog, Pc, Sc);
    scan_combine_kernel<<<(IDIM * NSTATE) / 256, 256, 0, stream>>>(Pc, Sc);
    scan_pass3_kernel<<<dim3(IDIM / 256, GCHUNK), 256, 0, stream>>>(
        dtlin, dtb, ssm, u16, proj, alog, Dp, Sc, y16);
    // out_proj split-K x2: (L,I)@(I,H) -> partials (aliases Wt1; Pc/Sc dead) -> out f32
    gemm_bt_kernel<float, 128><<<dim3(HID / 128, LSEQ / BM, 2), 256, 0, stream>>>(
        y16, Wt4, opart, LSEQ, HID, IDIM, IDIM / 2);
    opart_reduce_kernel<<<(LSEQ * HID) / 256, 256, 0, stream>>>(opart, out);
}

// Round 6
// 470.582 us; speedup vs baseline: 6.1555x; 1.0669x over previous
//
#include <hip/hip_runtime.h>
#include <stdint.h>

// Mamba-1.4B-like dims (fixed)
#define LSEQ 2048
#define HID  2048
#define IDIM 4096
#define NSTATE 16
#define RRANK 128
#define GDIM 160   // RRANK + 2*NSTATE

// chunked scan
#define GCHUNK 64
#define TCHUNK (LSEQ / GCHUNK)   // 32

typedef _Float16 f16x8 __attribute__((ext_vector_type(8)));
typedef _Float16 f16x2 __attribute__((ext_vector_type(2)));
typedef float f32x4 __attribute__((ext_vector_type(4)));

#define GLOAD_LDS16(g, l) __builtin_amdgcn_global_load_lds( \
    (const __attribute__((address_space(1))) void*)(g),     \
    (__attribute__((address_space(3))) void*)(l), 16, 0, 0)

__device__ __forceinline__ float softplus_f(float x) {
    if (x > 20.f) return x;
    return log1pf(__expf(x));
}
__device__ __forceinline__ float silu_f(float x) {
    return x / (1.f + __expf(-x));
}

// ---------------------------------------------------------------------------
// transpose one 64x64 tile of f32 (R x C) -> f16 (C x R)
__device__ __forceinline__ void transpose_tile(const float* __restrict__ in,
                                               _Float16* __restrict__ out,
                                               int R, int C, int tr, int tc,
                                               _Float16 (*tile)[66]) {
    const int c0 = tc * 64, r0 = tr * 64;
    const int t = threadIdx.x;
    const int tx = t & 15, ty = t >> 4;     // load: 16x16 threads, 4 cols each
    const int ox = t & 7, oy = t >> 3;      // store: 8x32 threads, 8 rows each
    const bool full = (c0 + 64 <= C) && (r0 + 64 <= R);
    if (full) {
        #pragma unroll
        for (int j = 0; j < 4; ++j) {
            int r = ty + j * 16;
            float4 v = *(const float4*)(in + (long)(r0 + r) * C + c0 + tx * 4);
            tile[r][tx * 4 + 0] = (_Float16)v.x;
            tile[r][tx * 4 + 1] = (_Float16)v.y;
            tile[r][tx * 4 + 2] = (_Float16)v.z;
            tile[r][tx * 4 + 3] = (_Float16)v.w;
        }
        __syncthreads();
        #pragma unroll
        for (int j = 0; j < 2; ++j) {
            int c = oy + j * 32;
            f16x8 v;
            #pragma unroll
            for (int e = 0; e < 8; ++e) v[e] = tile[ox * 8 + e][c];
            *(f16x8*)(out + (long)(c0 + c) * R + r0 + ox * 8) = v;
        }
    } else {
        #pragma unroll
        for (int j = 0; j < 4; ++j) {
            int r = ty + j * 16;
            #pragma unroll
            for (int e = 0; e < 4; ++e) {
                int c = c0 + tx * 4 + e;
                float v = (r0 + r < R && c < C) ? in[(long)(r0 + r) * C + c] : 0.f;
                tile[r][tx * 4 + e] = (_Float16)v;
            }
        }
        __syncthreads();
        #pragma unroll
        for (int j = 0; j < 2; ++j) {
            int c = c0 + oy + j * 32;
            if (c < C) {
                #pragma unroll
                for (int e = 0; e < 8; ++e) {
                    int r = r0 + ox * 8 + e;
                    if (r < R) out[(long)c * R + r] = tile[ox * 8 + e][oy + j * 32];
                }
            }
        }
    }
}

// ---------------------------------------------------------------------------
// One-shot prep: all 4 weight transposes (f32->f16 transposed) + X f32->f16.
// Block ranges: W1 4096 | W2 192 | W3 128 | W4 2048 | Xconv 1024  = 7488
__global__ __launch_bounds__(256)
void prep_kernel(const float* __restrict__ x_in, const float* __restrict__ w_in,
                 const float* __restrict__ xw, const float* __restrict__ dtw,
                 const float* __restrict__ ow,
                 _Float16* __restrict__ Xf, _Float16* __restrict__ Wt1,
                 _Float16* __restrict__ Wt2, _Float16* __restrict__ Wt3,
                 _Float16* __restrict__ Wt4) {
    __shared__ _Float16 tile[64][66];
    int b = blockIdx.x;
    if (b < 4096) { transpose_tile(w_in, Wt1, HID, 2 * IDIM, b / 128, b % 128, tile); return; }
    b -= 4096;
    if (b < 192) { transpose_tile(xw, Wt2, IDIM, GDIM, b / 3, b % 3, tile); return; }
    b -= 192;
    if (b < 128) { transpose_tile(dtw, Wt3, RRANK, IDIM, b / 64, b % 64, tile); return; }
    b -= 128;
    if (b < 2048) { transpose_tile(ow, Wt4, IDIM, HID, b / 32, b % 32, tile); return; }
    b -= 2048;
    // X convert: 4096 elements per block, 16 per thread
    long base = (long)b * 4096 + threadIdx.x * 16;
    #pragma unroll
    for (int h = 0; h < 2; ++h) {
        float4 a = *(const float4*)(x_in + base + h * 8);
        float4 c = *(const float4*)(x_in + base + h * 8 + 4);
        f16x8 v;
        v[0] = (_Float16)a.x; v[1] = (_Float16)a.y; v[2] = (_Float16)a.z; v[3] = (_Float16)a.w;
        v[4] = (_Float16)c.x; v[5] = (_Float16)c.y; v[6] = (_Float16)c.z; v[7] = (_Float16)c.w;
        *(f16x8*)(Xf + base + h * 8) = v;
    }
}

// ---------------------------------------------------------------------------
// GEMM: C = A(M,K) @ Bt(N,K)^T, fp16 in, fp32 acc. BM=128 fixed, BN_ in {64,128}.
// BK=64: global_load_lds 16B DMA staging; LDS rows of 64 f16 (8 chunks of 16B),
// chunk q of row r stored at slot q^(r&7) -> conflict-free ds_read_b128.
// K-split via blockIdx.z over [z*kc, z*kc+kc), output slab z.
// SOFTPLUS: store softplus(acc + bias[col]) (dt_proj fusion).
#define BM 128
#define BK 64

template <typename CT, int BN_, bool SOFTPLUS>
__global__ __launch_bounds__(256)
void gemm_bt_kernel(const _Float16* __restrict__ A, const _Float16* __restrict__ Bt,
                    CT* __restrict__ C, int M, int N, int K, int kc,
                    const float* __restrict__ bias) {
    constexpr int NI = BN_ / 32;           // 16-col tiles per wave
    constexpr int NISS_B = BN_ * 8 / 256;  // B staging issues per thread
    __shared__ _Float16 As[BM * BK];
    __shared__ _Float16 Bs[BN_ * BK];
    const int m0 = blockIdx.y * BM;
    const int n0 = blockIdx.x * BN_;
    const int t = threadIdx.x;
    const int wave = t >> 6;
    const int lane = t & 63;
    const int wm = wave >> 1, wn = wave & 1;
    const int lrow = lane & 15;
    const int quad = lane >> 4;
    const int sw8 = (lrow & 7) * 8;        // fragment-read XOR (in elements)

    f32x4 acc[4][NI];
    #pragma unroll
    for (int mi = 0; mi < 4; ++mi)
        #pragma unroll
        for (int ni = 0; ni < NI; ++ni)
            #pragma unroll
            for (int r = 0; r < 4; ++r)
                acc[mi][ni][r] = 0.f;

    const int k_begin = blockIdx.z * kc;
    const _Float16* pA[4];
    #pragma unroll
    for (int j = 0; j < 4; ++j) {
        int s = j * 256 + t;
        int row = s >> 3;
        int ch = (s & 7) ^ (row & 7);
        pA[j] = A + (long)(m0 + row) * K + ch * 8 + k_begin;
    }
    const _Float16* pB[NISS_B];
    #pragma unroll
    for (int j = 0; j < NISS_B; ++j) {
        int s = j * 256 + t;
        int row = s >> 3;
        int ch = (s & 7) ^ (row & 7);
        pB[j] = Bt + (long)(n0 + row) * K + ch * 8 + k_begin;
    }

    for (int kk = 0; kk < kc; kk += BK) {
        #pragma unroll
        for (int j = 0; j < 4; ++j) {
            GLOAD_LDS16(pA[j], As + (j * 256 + wave * 64) * 8);
            pA[j] += BK;
        }
        #pragma unroll
        for (int j = 0; j < NISS_B; ++j) {
            GLOAD_LDS16(pB[j], Bs + (j * 256 + wave * 64) * 8);
            pB[j] += BK;
        }
        __syncthreads();

        #pragma unroll
        for (int h = 0; h < 2; ++h) {
            const int qoff = (h * 32 + quad * 8) ^ sw8;
            f16x8 af[4], bf[NI];
            #pragma unroll
            for (int mi = 0; mi < 4; ++mi)
                af[mi] = *(const f16x8*)(As + (wm * 64 + mi * 16 + lrow) * BK + qoff);
            #pragma unroll
            for (int ni = 0; ni < NI; ++ni)
                bf[ni] = *(const f16x8*)(Bs + (wn * (BN_ / 2) + ni * 16 + lrow) * BK + qoff);
            #pragma unroll
            for (int mi = 0; mi < 4; ++mi)
                #pragma unroll
                for (int ni = 0; ni < NI; ++ni)
                    acc[mi][ni] = __builtin_amdgcn_mfma_f32_16x16x32_f16(af[mi], bf[ni], acc[mi][ni], 0, 0, 0);
        }
        __syncthreads();
    }

    CT* Cz = C + (long)blockIdx.z * M * N;
    #pragma unroll
    for (int mi = 0; mi < 4; ++mi) {
        #pragma unroll
        for (int ni = 0; ni < NI; ++ni) {
            int col = n0 + wn * (BN_ / 2) + ni * 16 + lrow;
            if (col < N) {
                float bv = SOFTPLUS ? bias[col] : 0.f;
                #pragma unroll
                for (int r = 0; r < 4; ++r) {
                    int row = m0 + wm * 64 + mi * 16 + quad * 4 + r;
                    float v = acc[mi][ni][r];
                    if (SOFTPLUS) v = softplus_f(v + bv);
                    Cz[(long)row * N + col] = (CT)v;
                }
            }
        }
    }
}

// ---------------------------------------------------------------------------
// x_proj split-K reduce: sum 8 partial slabs (L,256), write ssm (L,160) f32
// and dt_in (L,128) f16 in one pass.
__global__ void xproj_reduce_kernel(const float* __restrict__ part, float* __restrict__ ssm,
                                    _Float16* __restrict__ dtin) {
    int idx = blockIdx.x * 256 + threadIdx.x;
    if (idx >= LSEQ * GDIM) return;
    int t = idx / GDIM;
    int c = idx - t * GDIM;
    float v = 0.f;
    #pragma unroll
    for (int k = 0; k < 8; ++k)
        v += part[((long)k * LSEQ + t) * 256 + c];
    ssm[idx] = v;
    if (c < RRANK) dtin[t * RRANK + c] = (_Float16)v;
}

// ---------------------------------------------------------------------------
// out_proj split-K reduce: out = part0 + part1 (f32), float4-wide
__global__ void opart_reduce_kernel(const float* __restrict__ part, float* __restrict__ out) {
    int idx = blockIdx.x * 256 + threadIdx.x;   // L*H/4
    float4 a = ((const float4*)part)[idx];
    float4 b = ((const float4*)(part + (long)LSEQ * HID))[idx];
    ((float4*)out)[idx] = make_float4(a.x + b.x, a.y + b.y, a.z + b.z, a.w + b.w);
}

// ---------------------------------------------------------------------------
// depthwise causal conv (K=4) + bias + SiLU; 8 channels x 4 timesteps/thread
__global__ void conv_silu_kernel(const _Float16* __restrict__ proj, const float* __restrict__ w,
                                 const float* __restrict__ b, _Float16* __restrict__ u16) {
    int idx = blockIdx.x * 256 + threadIdx.x;   // (L/4) * (I/8)
    int i0 = (idx & 511) * 8;
    int t0 = (idx >> 9) * 4;
    f16x8 r[7];
    #pragma unroll
    for (int k = 0; k < 7; ++k) {
        int tt = t0 - 3 + k;
        if (tt >= 0) r[k] = *(const f16x8*)(proj + (long)tt * (2 * IDIM) + i0);
        else         r[k] = f16x8{0,0,0,0,0,0,0,0};
    }
    float4 wv[8]; float bb[8];
    #pragma unroll
    for (int j = 0; j < 8; ++j) { wv[j] = ((const float4*)w)[i0 + j]; bb[j] = b[i0 + j]; }
    #pragma unroll
    for (int tt = 0; tt < 4; ++tt) {
        f16x8 res;
        #pragma unroll
        for (int j = 0; j < 8; ++j) {
            float a = bb[j] + (float)r[tt][j] * wv[j].x + (float)r[tt+1][j] * wv[j].y
                            + (float)r[tt+2][j] * wv[j].z + (float)r[tt+3][j] * wv[j].w;
            res[j] = (_Float16)(a / (1.f + __expf(-a)));
        }
        *(f16x8*)(u16 + (long)(t0 + tt) * IDIM + i0) = res;
    }
}

// ---------------------------------------------------------------------------
// Chunked selective scan, 2 channels per thread, f16 chunk states.
// dtf already holds dt = softplus(dt_in @ dtW + dtb) (fused in dt_proj).
__global__ __launch_bounds__(256)
void scan_pass1_kernel(const _Float16* __restrict__ dtf, const float* __restrict__ ssm,
                       const _Float16* __restrict__ u16, const float* __restrict__ A_log,
                       _Float16* __restrict__ Pc, _Float16* __restrict__ Sc) {
    const int c = blockIdx.y;
    const int i0 = (blockIdx.x * 256 + threadIdx.x) * 2;

    __shared__ float Bs[TCHUNK * 16];
    for (int idx = threadIdx.x; idx < TCHUNK * 16; idx += 256) {
        int t = idx >> 4, n = idx & 15;
        Bs[idx] = ssm[(c * TCHUNK + t) * GDIM + RRANK + n];
    }
    __syncthreads();

    float A[2][16];
    #pragma unroll
    for (int ch = 0; ch < 2; ++ch) {
        const float4* Ap = (const float4*)(A_log + (long)(i0 + ch) * 16);
        #pragma unroll
        for (int q = 0; q < 4; ++q) {
            float4 v = Ap[q];
            A[ch][q * 4 + 0] = -__expf(v.x);
            A[ch][q * 4 + 1] = -__expf(v.y);
            A[ch][q * 4 + 2] = -__expf(v.z);
            A[ch][q * 4 + 3] = -__expf(v.w);
        }
    }

    float s[2][16], pr[2][16];
    #pragma unroll
    for (int ch = 0; ch < 2; ++ch)
        #pragma unroll
        for (int n = 0; n < 16; ++n) { s[ch][n] = 0.f; pr[ch][n] = 1.f; }

    long base = (long)c * TCHUNK * IDIM + i0;
    for (int t = 0; t < TCHUNK; ++t) {
        f16x2 dt2 = *(const f16x2*)(dtf + base + (long)t * IDIM);
        f16x2 u2  = *(const f16x2*)(u16 + base + (long)t * IDIM);
        #pragma unroll
        for (int ch = 0; ch < 2; ++ch) {
            float dt = (float)dt2[ch];
            float dtu = dt * (float)u2[ch];
            #pragma unroll
            for (int n = 0; n < 16; ++n) {
                float dA = __expf(dt * A[ch][n]);
                s[ch][n] = s[ch][n] * dA + dtu * Bs[t * 16 + n];
                pr[ch][n] *= dA;
            }
        }
    }

    long o = ((long)c * IDIM + i0) * 16;
    #pragma unroll
    for (int ch = 0; ch < 2; ++ch) {
        #pragma unroll
        for (int q = 0; q < 2; ++q) {
            f16x8 pv, sv;
            #pragma unroll
            for (int e = 0; e < 8; ++e) {
                pv[e] = (_Float16)pr[ch][q * 8 + e];
                sv[e] = (_Float16)s[ch][q * 8 + e];
            }
            *(f16x8*)(Pc + o + ch * 16 + q * 8) = pv;
            *(f16x8*)(Sc + o + ch * 16 + q * 8) = sv;
        }
    }
}

// Combine: sequential over G chunks per (i,n) pair (f16x2/thread), f32 carry,
// group-of-4 prefetch. Init overwrites Sc in place.
__global__ void scan_combine_kernel(const _Float16* __restrict__ Pc, _Float16* __restrict__ ScInit) {
    int tid = blockIdx.x * 256 + threadIdx.x;   // I*16/2 pairs
    const long stride = (long)IDIM * 16;
    const long off = (long)tid * 2;
    f16x2 p4[4], s4[4];
    #pragma unroll
    for (int k = 0; k < 4; ++k) {
        p4[k] = *(const f16x2*)(Pc + (long)k * stride + off);
        s4[k] = *(const f16x2*)(ScInit + (long)k * stride + off);
    }
    float c0 = 0.f, c1 = 0.f;
    for (int g = 0; g < GCHUNK / 4; ++g) {
        f16x2 pc[4], sc[4];
        #pragma unroll
        for (int k = 0; k < 4; ++k) { pc[k] = p4[k]; sc[k] = s4[k]; }
        if (g + 1 < GCHUNK / 4) {
            #pragma unroll
            for (int k = 0; k < 4; ++k) {
                long o2 = (long)((g + 1) * 4 + k) * stride + off;
                p4[k] = *(const f16x2*)(Pc + o2);
                s4[k] = *(const f16x2*)(ScInit + o2);
            }
        }
        #pragma unroll
        for (int k = 0; k < 4; ++k) {
            long o = (long)(g * 4 + k) * stride + off;
            *(f16x2*)(ScInit + o) = f16x2{(_Float16)c0, (_Float16)c1};
            c0 = c0 * (float)pc[k][0] + (float)sc[k][0];
            c1 = c1 * (float)pc[k][1] + (float)sc[k][1];
        }
    }
}

__global__ __launch_bounds__(256)
void scan_pass3_kernel(const _Float16* __restrict__ dtf, const float* __restrict__ ssm,
                       const _Float16* __restrict__ u16, const _Float16* __restrict__ proj,
                       const float* __restrict__ A_log, const float* __restrict__ Dp,
                       const _Float16* __restrict__ Init, _Float16* __restrict__ y16) {
    const int c = blockIdx.y;
    const int i0 = (blockIdx.x * 256 + threadIdx.x) * 2;

    __shared__ float Bs[TCHUNK * 16];
    __shared__ float Cs[TCHUNK * 16];
    for (int idx = threadIdx.x; idx < TCHUNK * 16; idx += 256) {
        int t = idx >> 4, n = idx & 15;
        Bs[idx] = ssm[(c * TCHUNK + t) * GDIM + RRANK + n];
        Cs[idx] = ssm[(c * TCHUNK + t) * GDIM + RRANK + NSTATE + n];
    }
    __syncthreads();

    float A[2][16];
    #pragma unroll
    for (int ch = 0; ch < 2; ++ch) {
        const float4* Ap = (const float4*)(A_log + (long)(i0 + ch) * 16);
        #pragma unroll
        for (int q = 0; q < 4; ++q) {
            float4 v = Ap[q];
            A[ch][q * 4 + 0] = -__expf(v.x);
            A[ch][q * 4 + 1] = -__expf(v.y);
            A[ch][q * 4 + 2] = -__expf(v.z);
            A[ch][q * 4 + 3] = -__expf(v.w);
        }
    }
    float2 Dv = *(const float2*)(Dp + i0);

    float s[2][16];
    {
        long o = ((long)c * IDIM + i0) * 16;
        #pragma unroll
        for (int ch = 0; ch < 2; ++ch)
            #pragma unroll
            for (int q = 0; q < 2; ++q) {
                f16x8 v = *(const f16x8*)(Init + o + ch * 16 + q * 8);
                #pragma unroll
                for (int e = 0; e < 8; ++e) s[ch][q * 8 + e] = (float)v[e];
            }
    }

    long base = (long)c * TCHUNK * IDIM + i0;
    for (int t = 0; t < TCHUNK; ++t) {
        f16x2 dt2 = *(const f16x2*)(dtf + base + (long)t * IDIM);
        f16x2 u2  = *(const f16x2*)(u16 + base + (long)t * IDIM);
        int tg = c * TCHUNK + t;
        f16x2 g2 = *(const f16x2*)(proj + (long)tg * (2 * IDIM) + IDIM + i0);
        f16x2 res;
        #pragma unroll
        for (int ch = 0; ch < 2; ++ch) {
            float dt = (float)dt2[ch];
            float uv = (float)u2[ch];
            float dtu = dt * uv;
            float y = 0.f;
            #pragma unroll
            for (int n = 0; n < 16; ++n) {
                float dA = __expf(dt * A[ch][n]);
                s[ch][n] = s[ch][n] * dA + dtu * Bs[t * 16 + n];
                y += s[ch][n] * Cs[t * 16 + n];
            }
            float g = (float)g2[ch];
            float Dch = ch ? Dv.y : Dv.x;
            res[ch] = (_Float16)((y + uv * Dch) * silu_f(g));
        }
        *(f16x2*)(y16 + base + (long)t * IDIM) = res;
    }
}

// ---------------------------------------------------------------------------
extern "C" void kernel_launch(void* const* d_in, const int* in_sizes, int n_in,
                              void* d_out, int out_size, void* d_ws, size_t ws_size,
                              hipStream_t stream) {
    const float* x_in  = (const float*)d_in[0];
    const float* w_in  = (const float*)d_in[1];
    const float* cw    = (const float*)d_in[2];
    const float* cb    = (const float*)d_in[3];
    const float* xw    = (const float*)d_in[4];
    const float* dtw   = (const float*)d_in[5];
    const float* dtb   = (const float*)d_in[6];
    const float* alog  = (const float*)d_in[7];
    const float* Dp    = (const float*)d_in[8];
    const float* ow    = (const float*)d_in[9];
    float* out = (float*)d_out;

    char* p = (char*)d_ws;
    auto alloc = [&](size_t bytes) { char* r = p; p += (bytes + 255) & ~255ull; return r; };
    _Float16* Xf    = (_Float16*)alloc((size_t)LSEQ * HID * 2);
    _Float16* Wt1   = (_Float16*)alloc((size_t)2 * IDIM * HID * 2);      // (2I, H); dead after in_proj
    _Float16* proj  = (_Float16*)alloc((size_t)LSEQ * 2 * IDIM * 2);
    _Float16* u16   = (_Float16*)alloc((size_t)LSEQ * IDIM * 2);
    _Float16* Wt2   = (_Float16*)alloc((size_t)256 * IDIM * 2);          // (GDIM pad 256, I)
    float*    ssm   = (float*)alloc((size_t)LSEQ * GDIM * 4);
    _Float16* dtin  = (_Float16*)alloc((size_t)LSEQ * RRANK * 2);
    _Float16* Wt3   = (_Float16*)alloc((size_t)IDIM * RRANK * 2);        // (I, R)
    _Float16* dtf   = (_Float16*)alloc((size_t)LSEQ * IDIM * 2);         // dt (softplus fused)
    _Float16* Wt4   = (_Float16*)alloc((size_t)HID * IDIM * 2);          // (H, I)
    _Float16* y16   = (_Float16*)alloc((size_t)LSEQ * IDIM * 2);

    // aliases into dead Wt1 region (33.5 MB), lifetime-ordered:
    //   xpart (until xproj_reduce) -> Pc/Sc f16 (scan) -> opart (out_proj split-K)
    float* xpart = (float*)Wt1;                        // 8 x 2048 x 256 f32
    _Float16* Pc = (_Float16*)Wt1;                     // G*I*16 f16 = 8.4 MB
    _Float16* Sc = Pc + (size_t)GCHUNK * IDIM * 16;    // G*I*16 f16
    float* opart = (float*)Wt1;                        // 2 x L*H f32 = 33.5 MB

    // 1. prep: 4 transposes + X convert (one launch)
    prep_kernel<<<7488, 256, 0, stream>>>(x_in, w_in, xw, dtw, ow, Xf, Wt1, Wt2, Wt3, Wt4);
    // 2. in_proj: (L,H)@(H,2I) -> proj f16
    gemm_bt_kernel<_Float16, 128, false><<<dim3(2 * IDIM / 128, LSEQ / BM, 1), 256, 0, stream>>>(
        Xf, Wt1, proj, LSEQ, 2 * IDIM, HID, HID, nullptr);
    // 3. conv + SiLU -> u16
    conv_silu_kernel<<<(LSEQ / 4) * (IDIM / 8) / 256, 256, 0, stream>>>(proj, cw, cb, u16);
    // 4. x_proj split-K x8: (L,I)@(I,256pad) -> partials
    gemm_bt_kernel<float, 128, false><<<dim3(2, LSEQ / BM, 8), 256, 0, stream>>>(
        u16, Wt2, xpart, LSEQ, 256, IDIM, IDIM / 8, nullptr);
    xproj_reduce_kernel<<<(LSEQ * GDIM + 255) / 256, 256, 0, stream>>>(xpart, ssm, dtin);
    // 5. dt_proj (+ fused bias & softplus): (L,R)@(R,I) -> dtf f16
    gemm_bt_kernel<_Float16, 128, true><<<dim3(IDIM / 128, LSEQ / BM, 1), 256, 0, stream>>>(
        dtin, Wt3, dtf, LSEQ, IDIM, RRANK, RRANK, dtb);
    // 6. chunked scan (2 ch/thread, f16 states)
    scan_pass1_kernel<<<dim3(IDIM / 512, GCHUNK), 256, 0, stream>>>(
        dtf, ssm, u16, alog, Pc, Sc);
    scan_combine_kernel<<<(IDIM * NSTATE / 2) / 256, 256, 0, stream>>>(Pc, Sc);
    scan_pass3_kernel<<<dim3(IDIM / 512, GCHUNK), 256, 0, stream>>>(
        dtf, ssm, u16, proj, alog, Dp, Sc, y16);
    // 7. out_proj split-K x2 -> partials (aliases Wt1) -> out f32
    gemm_bt_kernel<float, 128, false><<<dim3(HID / 128, LSEQ / BM, 2), 256, 0, stream>>>(
        y16, Wt4, opart, LSEQ, HID, IDIM, IDIM / 2, nullptr);
    opart_reduce_kernel<<<(LSEQ * HID / 4) / 256, 256, 0, stream>>>(opart, out);
}